// Round 2
// baseline (692.316 us; speedup 1.0000x reference)
//
#include <hip/hip_runtime.h>

#define NN 50000
#define EE 800000
#define DD 256
#define NB 196   // ceil(NN/256)

typedef unsigned short u16;
typedef unsigned int u32;

typedef __attribute__((ext_vector_type(8))) short short8;
typedef __attribute__((ext_vector_type(4))) float f32x4;
typedef __attribute__((ext_vector_type(2))) float f32x2;
typedef __attribute__((ext_vector_type(4))) unsigned short u16x4;
typedef __attribute__((ext_vector_type(4))) int i32x4;

__device__ __forceinline__ float b2f(u16 u) {
  union { u32 i; float f; } c; c.i = ((u32)u) << 16; return c.f;
}
__device__ __forceinline__ u16 f2b(float f) {
  union { float f; u32 i; } c; c.f = f;
  u32 u = c.i;
  return (u16)((u + 0x7fffu + ((u >> 16) & 1u)) >> 16);
}
// slope<1: lrelu(x) == max(x, 0.2x) exactly
__device__ __forceinline__ float lrelu(float x) { return fmaxf(x, 0.2f * x); }
__device__ __forceinline__ float ldf(const void* p, int i, int bf) {
  return bf ? b2f(((const u16*)p)[i]) : ((const float*)p)[i];
}
__device__ __forceinline__ int lde(const void* ei, int idx, int m64) {
  int v = m64 ? (int)((const long long*)ei)[idx] : ((const int*)ei)[idx];
  return v < 0 ? 0 : (v >= NN ? NN - 1 : v);
}
// softmax without online max: shift-invariant, scores bounded -> exact vs ref
__device__ __forceinline__ float cexp(float s) {
  return __expf(__builtin_amdgcn_fmed3f(s, -60.f, 60.f));
}

// ---- packed f32 VOP3P ops (compiler never auto-emits these; pure, no side effects) ----
__device__ __forceinline__ f32x2 pk_add(f32x2 a, f32x2 b) {
  f32x2 d; asm("v_pk_add_f32 %0, %1, %2" : "=v"(d) : "v"(a), "v"(b)); return d;
}
__device__ __forceinline__ f32x2 pk_mul(f32x2 a, f32x2 b) {
  f32x2 d; asm("v_pk_mul_f32 %0, %1, %2" : "=v"(d) : "v"(a), "v"(b)); return d;
}
__device__ __forceinline__ f32x2 pk_fma(f32x2 a, f32x2 b, f32x2 c) {
  f32x2 d; asm("v_pk_fma_f32 %0, %1, %2, %3" : "=v"(d) : "v"(a), "v"(b), "v"(c)); return d;
}

// ---- async global->LDS (16B/lane, dest = wave-uniform base + lane*16) ----
__device__ __forceinline__ void gload_lds16(const void* g, void* l) {
  __builtin_amdgcn_global_load_lds(
      (const __attribute__((address_space(1))) void*)g,
      (__attribute__((address_space(3))) void*)l, 16, 0, 0);
}

// ---------------- init: zero cnt + dtype detection (block 0, wave 0) ----------------
__global__ __launch_bounds__(256) void init_kernel(const void* x, const void* ei,
                                                   int* flags, int* cnt) {
  int i = blockIdx.x * 256 + threadIdx.x;
  if (i < NN) cnt[i] = 0;
  if (blockIdx.x == 0 && threadIdx.x < 64) {
    int lane = threadIdx.x;
    const u16* xw = (const u16*)x;
    int c = 0;
    for (int k = lane; k < 512; k += 64) {
      u16 w = xw[k];
      int e = (w >> 7) & 0xFF;
      if ((e >= 107 && e <= 147) || (w & 0x7FFF) == 0) ++c;
    }
    const u32* ew = (const u32*)ei;
    int zc = 0;
    for (int k = 1 + 2 * lane; k < 1024; k += 128)
      if (ew[k] == 0) ++zc;
    #pragma unroll
    for (int off = 1; off < 64; off <<= 1) {
      c += __shfl_xor(c, off);
      zc += __shfl_xor(zc, off);
    }
    if (lane == 0) {
      flags[0] = (c >= 440) ? 1 : 0;
      flags[1] = (zc >= 400) ? 1 : 0;
    }
  }
}

// ---------------- CSR build ----------------
__global__ void hist_kernel(const void* ei, const int* flags, int* cnt) {
  int e = blockIdx.x * 256 + threadIdx.x;
  if (e < EE) atomicAdd(&cnt[lde(ei, EE + e, flags[1])], 1);
}

// -------- parallel 3-phase exclusive scan of deg[NN] -> rowptr[NN+1] --------
__global__ __launch_bounds__(256) void bsum_kernel(const int* __restrict__ deg,
                                                   int* __restrict__ bsum) {
  int i = blockIdx.x * 256 + threadIdx.x;
  int v = (i < NN) ? deg[i] : 0;
  #pragma unroll
  for (int off = 1; off < 64; off <<= 1) v += __shfl_xor(v, off);
  __shared__ int ws[4];
  int lane = threadIdx.x & 63, wid = threadIdx.x >> 6;
  if (lane == 0) ws[wid] = v;
  __syncthreads();
  if (threadIdx.x == 0) bsum[blockIdx.x] = ws[0] + ws[1] + ws[2] + ws[3];
}

__global__ __launch_bounds__(256) void bscan_kernel(const int* __restrict__ bsum,
                                                    int* __restrict__ boff) {
  int t = threadIdx.x;
  int v = (t < NB) ? bsum[t] : 0;
  int iv = v;
  int lane = t & 63, wid = t >> 6;
  #pragma unroll
  for (int off = 1; off < 64; off <<= 1) {
    int u = __shfl_up(iv, off);
    if (lane >= off) iv += u;
  }
  __shared__ int ws[4];
  if (lane == 63) ws[wid] = iv;
  __syncthreads();
  int add = 0;
  for (int w = 0; w < wid; ++w) add += ws[w];
  if (t < NB) boff[t] = iv - v + add;
}

__global__ __launch_bounds__(256) void bwrite_kernel(const int* __restrict__ deg,
                                                     const int* __restrict__ boff,
                                                     int* __restrict__ rowptr) {
  int i = blockIdx.x * 256 + threadIdx.x;
  int v = (i < NN) ? deg[i] : 0;
  int iv = v;
  int lane = threadIdx.x & 63, wid = threadIdx.x >> 6;
  #pragma unroll
  for (int off = 1; off < 64; off <<= 1) {
    int u = __shfl_up(iv, off);
    if (lane >= off) iv += u;
  }
  __shared__ int ws[4];
  if (lane == 63) ws[wid] = iv;
  __syncthreads();
  int add = boff[blockIdx.x];
  for (int w = 0; w < wid; ++w) add += ws[w];
  if (i <= NN) rowptr[i] = iv - v + add;
}

// uses hist counts (cnt[dst]=deg) via atomicSub -> no second memset needed
__global__ void fill_kernel(const void* ei, const int* flags, const int* __restrict__ rowptr,
                            int* __restrict__ cnt, int* __restrict__ col) {
  int e = blockIdx.x * 256 + threadIdx.x;
  if (e < EE) {
    int m64 = flags[1];
    int dst = lde(ei, EE + e, m64);
    int old = atomicSub(&cnt[dst], 1);
    int pos = rowptr[dst] + old - 1;
    if (pos >= 0 && pos < EE) col[pos] = lde(ei, e, m64);
  }
}

// -------- prep: weight pack (MFMA B-frag order) + final-weight pack + x->bf16 --------
// grid 14084: [0,1536) pack wpack, [1536,1584) pack fwp, [1584,14084) convert x.
__global__ __launch_bounds__(256) void prep_kernel(
    const void* Wl, const void* Wr, const void* Wlin,
    const void* fWl, const void* fWr, const void* fWlin,
    const void* x, const int* flags, u16* wpack, u16* fwp, u16* xb) {
  int bf = flags[0];
  int bid = blockIdx.x;
  if (bid < 1536) {
    int idx = bid * 256 + threadIdx.x;
    int m = idx >> 16, e = idx & 65535;
    int layer = (m >= 3) ? 1 : 0, sel = m - layer * 3;
    const void* src = (sel == 0 ? Wl : (sel == 1 ? Wr : Wlin));
    int k = e >> 8, n = e & 255;
    wpack[(m << 16) + ((((k >> 3) << 8) + n) << 3) + (k & 7)] =
        f2b(ldf(src, layer * 65536 + e, bf));
  } else if (bid < 1584) {
    int idx = (bid - 1536) * 256 + threadIdx.x;
    int j = idx & 7;
    int col = (idx >> 3) % 48;
    int kk = idx / (48 * 8);
    int k = kk * 8 + j;
    float v = 0.f;
    if (col < 20)      v = ldf(fWl, k * 20 + col, bf);
    else if (col < 40) v = ldf(fWr, k * 20 + (col - 20), bf);
    else if (col < 45) v = ldf(fWlin, k * 5 + (col - 40), bf);
    fwp[idx] = f2b(v);
  } else {
    int base = (bid - 1584) * 1024 + threadIdx.x * 4;
    if (bf) {
      *(u16x4*)(xb + base) = *(const u16x4*)((const u16*)x + base);
    } else {
      f32x4 s = *(const f32x4*)((const float*)x + base);
      u16x4 o;
      #pragma unroll
      for (int j = 0; j < 4; ++j) o[j] = f2b(s[j]);
      *(u16x4*)(xb + base) = o;
    }
  }
}

// ------- fused GEMM: (M x 256) x (256 x 768), A-resident + LDS-staged B -------------
// B staging now uses global_load_lds (no VGPR round-trip); layout is lane-linear in
// both global and LDS so the wave-uniform-base + lane*16 destination rule holds.
__global__ __launch_bounds__(256) void gemm_kernel(
    const u16* __restrict__ A, const u16* __restrict__ wpack, const void* blin,
    const int* flags, int layer, float* __restrict__ sums,
    u16* __restrict__ xl, u16* __restrict__ xr, u16* __restrict__ lp, int M) {
  __shared__ __align__(16) u16 bsh[16384];   // 32 KB: [kk 0..31][col 0..63][j 0..7]
  if (blockIdx.x == 0 && blockIdx.y == 0) {
    sums[threadIdx.x] = 0.f;
    sums[threadIdx.x + 256] = 0.f;
  }
  int wave = threadIdx.x >> 6;
  int lane = threadIdx.x & 63;
  int q = lane >> 4;
  int t = lane & 15;
  int m0 = blockIdx.x * 64 + wave * 16;
  int yh = blockIdx.y;

  int arow = m0 + t;
  if (arow >= M) arow = M - 1;
  const u16* Abase = A + (size_t)arow * DD + q * 8;
  short8 af[8];
  #pragma unroll
  for (int i = 0; i < 8; ++i) af[i] = *(const short8*)(Abase + i * 32);

  int bf = flags[0];

  for (int yi = 0; yi < 6; ++yi) {
    int y = yh * 6 + yi;
    int m = y >> 2;
    int col0 = (y & 3) * 64;
    const u16* wb = wpack + (m << 16);

    __syncthreads();   // previous iteration's LDS reads complete
    #pragma unroll
    for (int itc = 0; itc < 8; ++itc) {
      int kk = wave + itc * 4;                       // = chunk>>6, uniform per wave
      const u16* gp = wb + (((kk << 8) + col0) << 3) + (lane << 3);
      u16* lb = &bsh[(wave * 64 + itc * 256) << 3];  // wave-uniform base
      gload_lds16(gp, lb);
    }
    __syncthreads();   // drains vmcnt (global_load_lds) before LDS reads

    f32x4 acc[4];
    #pragma unroll
    for (int ns = 0; ns < 4; ++ns) acc[ns] = (f32x4){0.f, 0.f, 0.f, 0.f};

    #pragma unroll
    for (int i = 0; i < 8; ++i) {
      int kk = i * 4 + q;
      const u16* bb = &bsh[(kk << 9) + (t << 3)];
      #pragma unroll
      for (int ns = 0; ns < 4; ++ns) {
        short8 b = *(const short8*)(bb + (ns << 7));
        acc[ns] = __builtin_amdgcn_mfma_f32_16x16x32_bf16(af[i], b, acc[ns], 0, 0, 0);
      }
    }

    u16* dstp = (y < 4) ? xl : (y < 8) ? xr : lp;
    bool isLp = (y >= 8);
    #pragma unroll
    for (int ns = 0; ns < 4; ++ns) {
      int c = col0 + ns * 16 + t;
      float bias = isLp ? ldf(blin, layer * 256 + c, bf) : 0.f;
      #pragma unroll
      for (int r = 0; r < 4; ++r) {
        int row = m0 + q * 4 + r;
        if (row < M) dstp[(size_t)row * DD + c] = f2b(acc[ns][r] + bias);
      }
    }
  }
}

// ---------------- final GEMM via MFMA: emb @ [fWl|fWr|fWlin] (256 -> 48 padded) ------
__global__ __launch_bounds__(256) void fgemm_kernel(
    const u16* __restrict__ A, const u16* __restrict__ fwp, const void* fblin,
    const int* flags, float* __restrict__ zl, float* __restrict__ zr,
    float* __restrict__ lp5, int M) {
  int wave = threadIdx.x >> 6;
  int lane = threadIdx.x & 63;
  int q = lane >> 4;
  int t = lane & 15;
  int m0 = blockIdx.x * 64 + wave * 16;

  f32x4 acc[3];
  #pragma unroll
  for (int ns = 0; ns < 3; ++ns) acc[ns] = (f32x4){0.f, 0.f, 0.f, 0.f};

  int arow = m0 + t;
  if (arow >= M) arow = M - 1;
  const u16* Abase = A + (size_t)arow * DD + q * 8;

  #pragma unroll
  for (int k0 = 0; k0 < DD; k0 += 32) {
    short8 a = *(const short8*)(Abase + k0);
    int kk = (k0 >> 3) + q;
    #pragma unroll
    for (int ns = 0; ns < 3; ++ns) {
      short8 b = *(const short8*)(fwp + (((kk * 48) + ns * 16 + t) << 3));
      acc[ns] = __builtin_amdgcn_mfma_f32_16x16x32_bf16(a, b, acc[ns], 0, 0, 0);
    }
  }

  int bf = flags[0];
  #pragma unroll
  for (int ns = 0; ns < 3; ++ns) {
    int c = ns * 16 + t;
    #pragma unroll
    for (int r = 0; r < 4; ++r) {
      int row = m0 + q * 4 + r;
      if (row < M) {
        float v = acc[ns][r];
        if (c < 20)      zl[row * 20 + c] = v;
        else if (c < 40) zr[row * 20 + (c - 20)] = v;
        else if (c < 45) lp5[row * 5 + (c - 40)] = v + ldf(fblin, c - 40, bf);
      }
    }
  }
}

// ------- GATv2 aggregation: 4 nodes/block (wave=node), packed-f32 VALU path ---------
struct AggCtx {
  f32x2 xr01, xr23, at01, at23, c02;
};

__device__ __forceinline__ void edge_step2(u16x4 s4, const AggCtx& C, float& l,
                                           f32x2& a01, f32x2& a23) {
  f32x2 x01, x23;
  x01.x = b2f(s4[0]); x01.y = b2f(s4[1]);
  x23.x = b2f(s4[2]); x23.y = b2f(s4[3]);
  f32x2 y01 = pk_add(x01, C.xr01);
  f32x2 y23 = pk_add(x23, C.xr23);
  f32x2 t01 = pk_mul(y01, C.c02);
  f32x2 t23 = pk_mul(y23, C.c02);
  f32x2 m01, m23;
  m01.x = fmaxf(y01.x, t01.x); m01.y = fmaxf(y01.y, t01.y);
  m23.x = fmaxf(y23.x, t23.x); m23.y = fmaxf(y23.y, t23.y);
  f32x2 sp2 = pk_fma(C.at23, m23, pk_mul(C.at01, m01));
  float sp = sp2.x + sp2.y;
  sp += __shfl_xor(sp, 1);
  sp += __shfl_xor(sp, 2);
  sp += __shfl_xor(sp, 4);
  sp += __shfl_xor(sp, 8);
  float pz = cexp(sp);
  l += pz;
  f32x2 pzp; pzp.x = pz; pzp.y = pz;
  a01 = pk_fma(pzp, x01, a01);
  a23 = pk_fma(pzp, x23, a23);
}

__global__ __launch_bounds__(256) void agg_kernel(
    const u16* __restrict__ xl, const u16* __restrict__ xr,
    const int* __restrict__ rowptr, const int* __restrict__ col,
    const void* att, const void* bconv, const int* flags, int layer,
    u16* __restrict__ cpart) {
  int wave = threadIdx.x >> 6;
  int node = blockIdx.x * 4 + wave;   // NN % 4 == 0, grid = NN/4
  int lane = threadIdx.x & 63;
  int h = lane >> 4;
  int cb = (lane & 15) * 4;
  int base = h * 64 + cb;
  int bf = flags[0];

  u16x4 r4 = *(const u16x4*)(xr + (size_t)node * DD + base);
  AggCtx C;
  C.xr01.x = b2f(r4[0]); C.xr01.y = b2f(r4[1]);
  C.xr23.x = b2f(r4[2]); C.xr23.y = b2f(r4[3]);
  C.at01.x = ldf(att, layer * 256 + base + 0, bf);
  C.at01.y = ldf(att, layer * 256 + base + 1, bf);
  C.at23.x = ldf(att, layer * 256 + base + 2, bf);
  C.at23.y = ldf(att, layer * 256 + base + 3, bf);
  C.c02.x = 0.2f; C.c02.y = 0.2f;

  float l = 0.f;
  f32x2 a01 = {0.f, 0.f}, a23 = {0.f, 0.f};
  int e0 = rowptr[node], e1 = rowptr[node + 1];
  const char* xlb = (const char*)xl;          // SGPR base; 32-bit voffset per gather
  u32 baseb = (u32)(base << 1);

  auto do_edge = [&](int c) {
    u32 off = ((u32)c << 9) + baseb;
    edge_step2(*(const u16x4*)(xlb + off), C, l, a01, a23);
  };

  int e = e0;
  for (; e < e1 && (e & 3); ++e) do_edge(col[e]);   // align to 16B for int4 col loads
  for (; e + 4 <= e1; e += 4) {
    i32x4 cq = *(const i32x4*)(col + e);
    u16x4 v0 = *(const u16x4*)(xlb + (((u32)cq.x << 9) + baseb));
    u16x4 v1 = *(const u16x4*)(xlb + (((u32)cq.y << 9) + baseb));
    u16x4 v2 = *(const u16x4*)(xlb + (((u32)cq.z << 9) + baseb));
    u16x4 v3 = *(const u16x4*)(xlb + (((u32)cq.w << 9) + baseb));
    edge_step2(v0, C, l, a01, a23);
    edge_step2(v1, C, l, a01, a23);
    edge_step2(v2, C, l, a01, a23);
    edge_step2(v3, C, l, a01, a23);
  }
  for (; e < e1; ++e) do_edge(col[e]);

  float inv = 1.f / (l + 1e-16f);
  float av[4] = {a01.x, a01.y, a23.x, a23.y};
  u16x4 outw;
  #pragma unroll
  for (int j = 0; j < 4; ++j)
    outw[j] = f2b(av[j] * inv + ldf(bconv, layer * 256 + base + j, bf));
  *(u16x4*)(cpart + (size_t)node * DD + base) = outw;
}

// ---------------- GraphNorm stats (bf16 input) ----------------
__global__ __launch_bounds__(256) void stats_kernel(const u16* __restrict__ cpart,
                                                    float* __restrict__ sums) {
  int ch = threadIdx.x;
  int n0 = blockIdx.x * 100, n1 = n0 + 100;
  float s = 0.f, s2 = 0.f;
  for (int n = n0; n < n1; ++n) {
    float x = b2f(cpart[(size_t)n * DD + ch]);
    s += x; s2 += x * x;
  }
  atomicAdd(&sums[ch], s);
  atomicAdd(&sums[256 + ch], s2);
}

// ---------------- GraphNorm + skip + ELU (bf16 cpart, u16x4-vectorized) -------------
__global__ __launch_bounds__(256) void norm_kernel(
    const u16* __restrict__ cpart, const u16* __restrict__ lp,
    const void* gw, const void* gb, const void* gms, const int* flags, int layer,
    const float* __restrict__ sums, u16* __restrict__ emb) {
  int t = threadIdx.x;
  int node = blockIdx.x * 4 + (t >> 6);     // NN % 4 == 0, grid = NN/4
  int c4 = (t & 63) * 4;
  int bf = flags[0];
  size_t idx = (size_t)node * DD + c4;
  const float invN = 1.f / (float)NN;
  u16x4 cp = *(const u16x4*)(cpart + idx);
  u16x4 lv = *(const u16x4*)(lp + idx);
  u16x4 o;
  #pragma unroll
  for (int j = 0; j < 4; ++j) {
    int ch = c4 + j;
    float mean = sums[ch] * invN;
    float ex2 = sums[256 + ch] * invN;
    float mm = mean * ldf(gms, layer * 256 + ch, bf);
    float var = ex2 - 2.f * mm * mean + mm * mm;
    float x = b2f(cp[j]);
    float y = ldf(gw, layer * 256 + ch, bf) * (x - mm) * rsqrtf(fmaxf(var, 0.f) + 1e-5f) +
              ldf(gb, layer * 256 + ch, bf) + b2f(lv[j]);
    o[j] = f2b(y > 0.f ? y : expm1f(y));
  }
  *(u16x4*)(emb + idx) = o;
}

// ---------------- final aggregation: 4 nodes/block, 16 edge-lanes/head --------------
__global__ __launch_bounds__(256) void finagg_kernel(
    const float* __restrict__ zl, const float* __restrict__ zr,
    const int* __restrict__ rowptr, const int* __restrict__ col,
    const void* fatt, const void* fbconv, const int* flags,
    const float* __restrict__ lp5, void* outv) {
  int node = blockIdx.x * 4 + (threadIdx.x >> 6);   // NN % 4 == 0, grid = NN/4
  int lane = threadIdx.x & 63;
  int bf = flags[0];
  int h = lane >> 4, sub = lane & 15;

  float zrv[5], atv[5];
  #pragma unroll
  for (int c = 0; c < 5; ++c) {
    zrv[c] = zr[node * 20 + h * 5 + c];
    atv[c] = ldf(fatt, h * 5 + c, bf);
  }
  float l = 0.f, acc[5] = {0.f, 0.f, 0.f, 0.f, 0.f};
  int e0 = rowptr[node], e1 = rowptr[node + 1];
  for (int e = e0 + sub; e < e1; e += 16) {
    int src = col[e];
    const float* zs = zl + src * 20 + h * 5;
    float zlv[5];
    #pragma unroll
    for (int c = 0; c < 5; ++c) zlv[c] = zs[c];
    float s = 0.f;
    #pragma unroll
    for (int c = 0; c < 5; ++c) s += atv[c] * lrelu(zlv[c] + zrv[c]);
    float pz = cexp(s);
    l += pz;
    #pragma unroll
    for (int c = 0; c < 5; ++c) acc[c] += pz * zlv[c];
  }
  #pragma unroll
  for (int off = 1; off < 16; off <<= 1) {
    l += __shfl_xor(l, off);
    #pragma unroll
    for (int c = 0; c < 5; ++c) acc[c] += __shfl_xor(acc[c], off);
  }
  float inv = 1.f / (l + 1e-16f);
  float v[5];
  #pragma unroll
  for (int c = 0; c < 5; ++c) {
    float tv = acc[c] * inv;
    tv += __shfl_xor(tv, 16);
    tv += __shfl_xor(tv, 32);
    v[c] = tv * 0.25f;
  }
  if (lane == 0) {
    float mx = -3.0e38f;
    #pragma unroll
    for (int c = 0; c < 5; ++c) {
      v[c] += ldf(fbconv, c, bf) + lp5[node * 5 + c];
      mx = fmaxf(mx, v[c]);
    }
    float se = 0.f;
    #pragma unroll
    for (int c = 0; c < 5; ++c) se += __expf(v[c] - mx);
    float lse = mx + __logf(se);
    #pragma unroll
    for (int c = 0; c < 5; ++c) {
      float r = v[c] - lse;
      if (bf) ((u16*)outv)[node * 5 + c] = f2b(r);
      else    ((float*)outv)[node * 5 + c] = r;
    }
  }
}

extern "C" void kernel_launch(void* const* d_in, const int* in_sizes, int n_in,
                              void* d_out, int out_size, void* d_ws, size_t ws_size,
                              hipStream_t stream) {
  (void)in_sizes; (void)n_in; (void)out_size; (void)ws_size;
  const void* x     = d_in[0];
  const void* ei    = d_in[1];
  const void* Wl    = d_in[2];
  const void* Wr    = d_in[3];
  const void* att   = d_in[4];
  const void* bconv = d_in[5];
  const void* Wlin  = d_in[6];
  const void* blin  = d_in[7];
  const void* gnw   = d_in[8];
  const void* gnb   = d_in[9];
  const void* gnms  = d_in[10];
  const void* fWl   = d_in[11];
  const void* fWr   = d_in[12];
  const void* fatt  = d_in[13];
  const void* fbc   = d_in[14];
  const void* fWlin = d_in[15];
  const void* fblin = d_in[16];

  char* p = (char*)d_ws;
  auto take = [&](size_t bytes) {
    char* r = p;
    p += (bytes + 511) & ~(size_t)511;
    return r;
  };
  int* flags   = (int*)take(512);
  int* rowptr  = (int*)take((NN + 1) * sizeof(int));
  int* cnt     = (int*)take(NN * sizeof(int));
  int* colx    = (int*)take(EE * sizeof(int));
  int* bsum    = (int*)take(256 * sizeof(int));
  int* boff    = (int*)take(256 * sizeof(int));
  u16* wpack   = (u16*)take((size_t)6 * 65536 * sizeof(u16));
  u16* fwp     = (u16*)take((size_t)32 * 48 * 8 * sizeof(u16));
  float* sums  = (float*)take(512 * sizeof(float));
  // unionA: xb (layer-1 GEMM input) -> cpart bf16 (agg out) -> zl/zr/lp5 (final).
  char* unionA = take((size_t)NN * DD * 4);
  u16* xb      = (u16*)unionA;
  u16* cpart   = (u16*)unionA;
  float* zl    = (float*)unionA;
  float* zr    = (float*)(unionA + (size_t)NN * 20 * 4);
  float* lp5   = (float*)(unionA + (size_t)NN * 40 * 4);
  u16* xl      = (u16*)take((size_t)NN * DD * 2);
  u16* xr      = (u16*)take((size_t)NN * DD * 2);
  u16* lp      = (u16*)take((size_t)NN * DD * 2);
  u16* emb     = (u16*)take((size_t)NN * DD * 2);

  init_kernel<<<dim3(NB), dim3(256), 0, stream>>>(x, ei, flags, cnt);
  hist_kernel<<<dim3((EE + 255) / 256), dim3(256), 0, stream>>>(ei, flags, cnt);
  bsum_kernel<<<dim3(NB), dim3(256), 0, stream>>>(cnt, bsum);
  bscan_kernel<<<dim3(1), dim3(256), 0, stream>>>(bsum, boff);
  bwrite_kernel<<<dim3(NB), dim3(256), 0, stream>>>(cnt, boff, rowptr);
  fill_kernel<<<dim3((EE + 255) / 256), dim3(256), 0, stream>>>(ei, flags, rowptr, cnt, colx);
  prep_kernel<<<dim3(1584 + NN * DD / 1024), dim3(256), 0, stream>>>(
      Wl, Wr, Wlin, fWl, fWr, fWlin, x, flags, wpack, fwp, xb);

  const u16* layerin = xb;
  for (int i = 0; i < 2; ++i) {
    gemm_kernel<<<dim3((NN + 63) / 64, 2), dim3(256), 0, stream>>>(
        layerin, wpack + (size_t)i * 3 * 65536, blin, flags, i, sums, xl, xr, lp, NN);
    agg_kernel<<<dim3(NN / 4), dim3(256), 0, stream>>>(xl, xr, rowptr, colx, att, bconv,
                                                       flags, i, cpart);
    stats_kernel<<<dim3(500), dim3(256), 0, stream>>>(cpart, sums);
    norm_kernel<<<dim3(NN / 4), dim3(256), 0, stream>>>(cpart, lp, gnw, gnb, gnms, flags, i,
                                                        sums, emb);
    layerin = emb;
  }
  fgemm_kernel<<<dim3((NN + 63) / 64), dim3(256), 0, stream>>>(emb, fwp, fblin, flags,
                                                               zl, zr, lp5, NN);
  finagg_kernel<<<dim3(NN / 4), dim3(256), 0, stream>>>(zl, zr, rowptr, colx, fatt, fbc,
                                                        flags, lp5, d_out);
}

// Round 3
// 656.019 us; speedup vs baseline: 1.0553x; 1.0553x over previous
//
#include <hip/hip_runtime.h>

#define NN 50000
#define EE 800000
#define DD 256
#define NB 196   // ceil(NN/256)

typedef unsigned short u16;
typedef unsigned int u32;

typedef __attribute__((ext_vector_type(8))) short short8;
typedef __attribute__((ext_vector_type(4))) float f32x4;
typedef __attribute__((ext_vector_type(4))) unsigned short u16x4;
typedef __attribute__((ext_vector_type(4))) int i32x4;

__device__ __forceinline__ float b2f(u16 u) {
  union { u32 i; float f; } c; c.i = ((u32)u) << 16; return c.f;
}
__device__ __forceinline__ u16 f2b(float f) {
  union { float f; u32 i; } c; c.f = f;
  u32 u = c.i;
  return (u16)((u + 0x7fffu + ((u >> 16) & 1u)) >> 16);
}
// slope<1: lrelu(x) == max(x, 0.2x) exactly
__device__ __forceinline__ float lrelu(float x) { return fmaxf(x, 0.2f * x); }
__device__ __forceinline__ float ldf(const void* p, int i, int bf) {
  return bf ? b2f(((const u16*)p)[i]) : ((const float*)p)[i];
}
__device__ __forceinline__ int lde(const void* ei, int idx, int m64) {
  int v = m64 ? (int)((const long long*)ei)[idx] : ((const int*)ei)[idx];
  return v < 0 ? 0 : (v >= NN ? NN - 1 : v);
}
// softmax without online max: shift-invariant, scores bounded -> exact vs ref
__device__ __forceinline__ float cexp(float s) {
  return __expf(__builtin_amdgcn_fmed3f(s, -60.f, 60.f));
}

// ---- DPP 16-lane butterfly add: bit-identical to shfl_xor{1,2,4,8} chain ----
// quad_perm[1,0,3,2]=0xB1 (xor1), quad_perm[2,3,0,1]=0x4E (xor2),
// row_half_mirror=0x141 (== xor4 once quad-uniform), row_mirror=0x140 (== xor8).
template <int CTRL>
__device__ __forceinline__ float dpp_add(float s) {
  union { float f; int i; } a, b;
  a.f = s;
  b.i = __builtin_amdgcn_update_dpp(0, a.i, CTRL, 0xf, 0xf, true);
  return s + b.f;
}
__device__ __forceinline__ float row16_allsum(float s) {
  s = dpp_add<0xB1>(s);
  s = dpp_add<0x4E>(s);
  s = dpp_add<0x141>(s);
  s = dpp_add<0x140>(s);
  return s;
}

// ---- async global->LDS (16B/lane, dest = wave-uniform base + lane*16) ----
__device__ __forceinline__ void gload_lds16(const void* g, void* l) {
  __builtin_amdgcn_global_load_lds(
      (const __attribute__((address_space(1))) void*)g,
      (__attribute__((address_space(3))) void*)l, 16, 0, 0);
}

// ---------------- init: zero cnt + dtype detection (block 0, wave 0) ----------------
__global__ __launch_bounds__(256) void init_kernel(const void* x, const void* ei,
                                                   int* flags, int* cnt) {
  int i = blockIdx.x * 256 + threadIdx.x;
  if (i < NN) cnt[i] = 0;
  if (blockIdx.x == 0 && threadIdx.x < 64) {
    int lane = threadIdx.x;
    const u16* xw = (const u16*)x;
    int c = 0;
    for (int k = lane; k < 512; k += 64) {
      u16 w = xw[k];
      int e = (w >> 7) & 0xFF;
      if ((e >= 107 && e <= 147) || (w & 0x7FFF) == 0) ++c;
    }
    const u32* ew = (const u32*)ei;
    int zc = 0;
    for (int k = 1 + 2 * lane; k < 1024; k += 128)
      if (ew[k] == 0) ++zc;
    #pragma unroll
    for (int off = 1; off < 64; off <<= 1) {
      c += __shfl_xor(c, off);
      zc += __shfl_xor(zc, off);
    }
    if (lane == 0) {
      flags[0] = (c >= 440) ? 1 : 0;
      flags[1] = (zc >= 400) ? 1 : 0;
    }
  }
}

// ---------------- CSR build ----------------
__global__ void hist_kernel(const void* ei, const int* flags, int* cnt) {
  int e = blockIdx.x * 256 + threadIdx.x;
  if (e < EE) atomicAdd(&cnt[lde(ei, EE + e, flags[1])], 1);
}

// -------- parallel 3-phase exclusive scan of deg[NN] -> rowptr[NN+1] --------
__global__ __launch_bounds__(256) void bsum_kernel(const int* __restrict__ deg,
                                                   int* __restrict__ bsum) {
  int i = blockIdx.x * 256 + threadIdx.x;
  int v = (i < NN) ? deg[i] : 0;
  #pragma unroll
  for (int off = 1; off < 64; off <<= 1) v += __shfl_xor(v, off);
  __shared__ int ws[4];
  int lane = threadIdx.x & 63, wid = threadIdx.x >> 6;
  if (lane == 0) ws[wid] = v;
  __syncthreads();
  if (threadIdx.x == 0) bsum[blockIdx.x] = ws[0] + ws[1] + ws[2] + ws[3];
}

__global__ __launch_bounds__(256) void bscan_kernel(const int* __restrict__ bsum,
                                                    int* __restrict__ boff) {
  int t = threadIdx.x;
  int v = (t < NB) ? bsum[t] : 0;
  int iv = v;
  int lane = t & 63, wid = t >> 6;
  #pragma unroll
  for (int off = 1; off < 64; off <<= 1) {
    int u = __shfl_up(iv, off);
    if (lane >= off) iv += u;
  }
  __shared__ int ws[4];
  if (lane == 63) ws[wid] = iv;
  __syncthreads();
  int add = 0;
  for (int w = 0; w < wid; ++w) add += ws[w];
  if (t < NB) boff[t] = iv - v + add;
}

__global__ __launch_bounds__(256) void bwrite_kernel(const int* __restrict__ deg,
                                                     const int* __restrict__ boff,
                                                     int* __restrict__ rowptr) {
  int i = blockIdx.x * 256 + threadIdx.x;
  int v = (i < NN) ? deg[i] : 0;
  int iv = v;
  int lane = threadIdx.x & 63, wid = threadIdx.x >> 6;
  #pragma unroll
  for (int off = 1; off < 64; off <<= 1) {
    int u = __shfl_up(iv, off);
    if (lane >= off) iv += u;
  }
  __shared__ int ws[4];
  if (lane == 63) ws[wid] = iv;
  __syncthreads();
  int add = boff[blockIdx.x];
  for (int w = 0; w < wid; ++w) add += ws[w];
  if (i <= NN) rowptr[i] = iv - v + add;
}

// uses hist counts (cnt[dst]=deg) via atomicSub -> no second memset needed
__global__ void fill_kernel(const void* ei, const int* flags, const int* __restrict__ rowptr,
                            int* __restrict__ cnt, int* __restrict__ col) {
  int e = blockIdx.x * 256 + threadIdx.x;
  if (e < EE) {
    int m64 = flags[1];
    int dst = lde(ei, EE + e, m64);
    int old = atomicSub(&cnt[dst], 1);
    int pos = rowptr[dst] + old - 1;
    if (pos >= 0 && pos < EE) col[pos] = lde(ei, e, m64);
  }
}

// -------- prep: weight pack (MFMA B-frag order) + final-weight pack + x->bf16 --------
// grid 14084: [0,1536) pack wpack, [1536,1584) pack fwp, [1584,14084) convert x.
__global__ __launch_bounds__(256) void prep_kernel(
    const void* Wl, const void* Wr, const void* Wlin,
    const void* fWl, const void* fWr, const void* fWlin,
    const void* x, const int* flags, u16* wpack, u16* fwp, u16* xb) {
  int bf = flags[0];
  int bid = blockIdx.x;
  if (bid < 1536) {
    int idx = bid * 256 + threadIdx.x;
    int m = idx >> 16, e = idx & 65535;
    int layer = (m >= 3) ? 1 : 0, sel = m - layer * 3;
    const void* src = (sel == 0 ? Wl : (sel == 1 ? Wr : Wlin));
    int k = e >> 8, n = e & 255;
    wpack[(m << 16) + ((((k >> 3) << 8) + n) << 3) + (k & 7)] =
        f2b(ldf(src, layer * 65536 + e, bf));
  } else if (bid < 1584) {
    int idx = (bid - 1536) * 256 + threadIdx.x;
    int j = idx & 7;
    int col = (idx >> 3) % 48;
    int kk = idx / (48 * 8);
    int k = kk * 8 + j;
    float v = 0.f;
    if (col < 20)      v = ldf(fWl, k * 20 + col, bf);
    else if (col < 40) v = ldf(fWr, k * 20 + (col - 20), bf);
    else if (col < 45) v = ldf(fWlin, k * 5 + (col - 40), bf);
    fwp[idx] = f2b(v);
  } else {
    int base = (bid - 1584) * 1024 + threadIdx.x * 4;
    if (bf) {
      *(u16x4*)(xb + base) = *(const u16x4*)((const u16*)x + base);
    } else {
      f32x4 s = *(const f32x4*)((const float*)x + base);
      u16x4 o;
      #pragma unroll
      for (int j = 0; j < 4; ++j) o[j] = f2b(s[j]);
      *(u16x4*)(xb + base) = o;
    }
  }
}

// ------- fused GEMM: (M x 256) x (256 x 768), A-resident + LDS-staged B -------------
// B staging via global_load_lds (no VGPR round-trip); layout is lane-linear in
// both global and LDS so the wave-uniform-base + lane*16 destination rule holds.
__global__ __launch_bounds__(256) void gemm_kernel(
    const u16* __restrict__ A, const u16* __restrict__ wpack, const void* blin,
    const int* flags, int layer, float* __restrict__ sums,
    u16* __restrict__ xl, u16* __restrict__ xr, u16* __restrict__ lp, int M) {
  __shared__ __align__(16) u16 bsh[16384];   // 32 KB: [kk 0..31][col 0..63][j 0..7]
  if (blockIdx.x == 0 && blockIdx.y == 0) {
    sums[threadIdx.x] = 0.f;
    sums[threadIdx.x + 256] = 0.f;
  }
  int wave = threadIdx.x >> 6;
  int lane = threadIdx.x & 63;
  int q = lane >> 4;
  int t = lane & 15;
  int m0 = blockIdx.x * 64 + wave * 16;
  int yh = blockIdx.y;

  int arow = m0 + t;
  if (arow >= M) arow = M - 1;
  const u16* Abase = A + (size_t)arow * DD + q * 8;
  short8 af[8];
  #pragma unroll
  for (int i = 0; i < 8; ++i) af[i] = *(const short8*)(Abase + i * 32);

  int bf = flags[0];

  for (int yi = 0; yi < 6; ++yi) {
    int y = yh * 6 + yi;
    int m = y >> 2;
    int col0 = (y & 3) * 64;
    const u16* wb = wpack + (m << 16);

    __syncthreads();   // previous iteration's LDS reads complete
    #pragma unroll
    for (int itc = 0; itc < 8; ++itc) {
      int kk = wave + itc * 4;                       // = chunk>>6, uniform per wave
      const u16* gp = wb + (((kk << 8) + col0) << 3) + (lane << 3);
      u16* lb = &bsh[(wave * 64 + itc * 256) << 3];  // wave-uniform base
      gload_lds16(gp, lb);
    }
    __syncthreads();   // drains vmcnt (global_load_lds) before LDS reads

    f32x4 acc[4];
    #pragma unroll
    for (int ns = 0; ns < 4; ++ns) acc[ns] = (f32x4){0.f, 0.f, 0.f, 0.f};

    #pragma unroll
    for (int i = 0; i < 8; ++i) {
      int kk = i * 4 + q;
      const u16* bb = &bsh[(kk << 9) + (t << 3)];
      #pragma unroll
      for (int ns = 0; ns < 4; ++ns) {
        short8 b = *(const short8*)(bb + (ns << 7));
        acc[ns] = __builtin_amdgcn_mfma_f32_16x16x32_bf16(af[i], b, acc[ns], 0, 0, 0);
      }
    }

    u16* dstp = (y < 4) ? xl : (y < 8) ? xr : lp;
    bool isLp = (y >= 8);
    #pragma unroll
    for (int ns = 0; ns < 4; ++ns) {
      int c = col0 + ns * 16 + t;
      float bias = isLp ? ldf(blin, layer * 256 + c, bf) : 0.f;
      #pragma unroll
      for (int r = 0; r < 4; ++r) {
        int row = m0 + q * 4 + r;
        if (row < M) dstp[(size_t)row * DD + c] = f2b(acc[ns][r] + bias);
      }
    }
  }
}

// ------ final GEMM via MFMA: emb @ [fWl|fWr|fWlin] -> zl/zr padded [N][32], lp [N][8]
__global__ __launch_bounds__(256) void fgemm_kernel(
    const u16* __restrict__ A, const u16* __restrict__ fwp, const void* fblin,
    const int* flags, float* __restrict__ zl, float* __restrict__ zr,
    float* __restrict__ lp5, int M) {
  int wave = threadIdx.x >> 6;
  int lane = threadIdx.x & 63;
  int q = lane >> 4;
  int t = lane & 15;
  int m0 = blockIdx.x * 64 + wave * 16;

  f32x4 acc[3];
  #pragma unroll
  for (int ns = 0; ns < 3; ++ns) acc[ns] = (f32x4){0.f, 0.f, 0.f, 0.f};

  int arow = m0 + t;
  if (arow >= M) arow = M - 1;
  const u16* Abase = A + (size_t)arow * DD + q * 8;

  #pragma unroll
  for (int k0 = 0; k0 < DD; k0 += 32) {
    short8 a = *(const short8*)(Abase + k0);
    int kk = (k0 >> 3) + q;
    #pragma unroll
    for (int ns = 0; ns < 3; ++ns) {
      short8 b = *(const short8*)(fwp + (((kk * 48) + ns * 16 + t) << 3));
      acc[ns] = __builtin_amdgcn_mfma_f32_16x16x32_bf16(a, b, acc[ns], 0, 0, 0);
    }
  }

  int bf = flags[0];
  #pragma unroll
  for (int ns = 0; ns < 3; ++ns) {
    int c = ns * 16 + t;
    #pragma unroll
    for (int r = 0; r < 4; ++r) {
      int row = m0 + q * 4 + r;
      if (row < M) {
        float v = acc[ns][r];
        if (c < 20) {
          zl[row * 32 + (c / 5) * 8 + (c % 5)] = v;
        } else if (c < 40) {
          int c2 = c - 20;
          zr[row * 32 + (c2 / 5) * 8 + (c2 % 5)] = v;
        } else if (c < 45) {
          lp5[row * 8 + (c - 40)] = v + ldf(fblin, c - 40, bf);
        }
      }
    }
  }
}

// ------- GATv2 aggregation: 4 nodes/block (wave=node), scalar math + DPP reduce -----
__device__ __forceinline__ void edge_step(u16x4 s4, const float* xrv, const float* atv,
                                          float& l, float* acc) {
  float x0 = b2f(s4[0]), x1 = b2f(s4[1]), x2 = b2f(s4[2]), x3 = b2f(s4[3]);
  float sp = atv[0] * lrelu(x0 + xrv[0]) + atv[1] * lrelu(x1 + xrv[1]) +
             atv[2] * lrelu(x2 + xrv[2]) + atv[3] * lrelu(x3 + xrv[3]);
  sp = row16_allsum(sp);        // bit-identical to shfl_xor{1,2,4,8}, zero DS ops
  float pz = cexp(sp);
  l += pz;
  acc[0] += pz * x0;
  acc[1] += pz * x1;
  acc[2] += pz * x2;
  acc[3] += pz * x3;
}

__global__ __launch_bounds__(256) void agg_kernel(
    const u16* __restrict__ xl, const u16* __restrict__ xr,
    const int* __restrict__ rowptr, const int* __restrict__ col,
    const void* att, const void* bconv, const int* flags, int layer,
    u16* __restrict__ cpart) {
  int wave = threadIdx.x >> 6;
  int node = blockIdx.x * 4 + wave;   // NN % 4 == 0, grid = NN/4
  int lane = threadIdx.x & 63;
  int h = lane >> 4;
  int cb = (lane & 15) * 4;
  int base = h * 64 + cb;
  int bf = flags[0];

  u16x4 r4 = *(const u16x4*)(xr + (size_t)node * DD + base);
  float xrv[4], atv[4];
  #pragma unroll
  for (int j = 0; j < 4; ++j) {
    xrv[j] = b2f(r4[j]);
    atv[j] = ldf(att, layer * 256 + base + j, bf);
  }

  float l = 0.f;
  float acc[4] = {0.f, 0.f, 0.f, 0.f};
  int e0 = rowptr[node], e1 = rowptr[node + 1];
  const char* xlb = (const char*)xl;          // SGPR base; 32-bit voffset per gather
  u32 baseb = (u32)(base << 1);

  int e = e0;
  for (; e < e1 && (e & 3); ++e) {            // align to 16B for int4 col loads
    u16x4 v = *(const u16x4*)(xlb + (((u32)col[e] << 9) + baseb));
    edge_step(v, xrv, atv, l, acc);
  }
  for (; e + 4 <= e1; e += 4) {
    i32x4 cq = *(const i32x4*)(col + e);
    u16x4 v0 = *(const u16x4*)(xlb + (((u32)cq.x << 9) + baseb));
    u16x4 v1 = *(const u16x4*)(xlb + (((u32)cq.y << 9) + baseb));
    u16x4 v2 = *(const u16x4*)(xlb + (((u32)cq.z << 9) + baseb));
    u16x4 v3 = *(const u16x4*)(xlb + (((u32)cq.w << 9) + baseb));
    edge_step(v0, xrv, atv, l, acc);
    edge_step(v1, xrv, atv, l, acc);
    edge_step(v2, xrv, atv, l, acc);
    edge_step(v3, xrv, atv, l, acc);
  }
  for (; e < e1; ++e) {
    u16x4 v = *(const u16x4*)(xlb + (((u32)col[e] << 9) + baseb));
    edge_step(v, xrv, atv, l, acc);
  }

  float inv = 1.f / (l + 1e-16f);
  u16x4 outw;
  #pragma unroll
  for (int j = 0; j < 4; ++j)
    outw[j] = f2b(acc[j] * inv + ldf(bconv, layer * 256 + base + j, bf));
  *(u16x4*)(cpart + (size_t)node * DD + base) = outw;
}

// ---------------- GraphNorm stats (bf16 input) ----------------
__global__ __launch_bounds__(256) void stats_kernel(const u16* __restrict__ cpart,
                                                    float* __restrict__ sums) {
  int ch = threadIdx.x;
  int n0 = blockIdx.x * 100, n1 = n0 + 100;
  float s = 0.f, s2 = 0.f;
  for (int n = n0; n < n1; ++n) {
    float x = b2f(cpart[(size_t)n * DD + ch]);
    s += x; s2 += x * x;
  }
  atomicAdd(&sums[ch], s);
  atomicAdd(&sums[256 + ch], s2);
}

// ---------------- GraphNorm + skip + ELU (bf16 cpart, u16x4-vectorized) -------------
__global__ __launch_bounds__(256) void norm_kernel(
    const u16* __restrict__ cpart, const u16* __restrict__ lp,
    const void* gw, const void* gb, const void* gms, const int* flags, int layer,
    const float* __restrict__ sums, u16* __restrict__ emb) {
  int t = threadIdx.x;
  int node = blockIdx.x * 4 + (t >> 6);     // NN % 4 == 0, grid = NN/4
  int c4 = (t & 63) * 4;
  int bf = flags[0];
  size_t idx = (size_t)node * DD + c4;
  const float invN = 1.f / (float)NN;
  u16x4 cp = *(const u16x4*)(cpart + idx);
  u16x4 lv = *(const u16x4*)(lp + idx);
  u16x4 o;
  #pragma unroll
  for (int j = 0; j < 4; ++j) {
    int ch = c4 + j;
    float mean = sums[ch] * invN;
    float ex2 = sums[256 + ch] * invN;
    float mm = mean * ldf(gms, layer * 256 + ch, bf);
    float var = ex2 - 2.f * mm * mean + mm * mm;
    float x = b2f(cp[j]);
    float y = ldf(gw, layer * 256 + ch, bf) * (x - mm) * rsqrtf(fmaxf(var, 0.f) + 1e-5f) +
              ldf(gb, layer * 256 + ch, bf) + b2f(lv[j]);
    o[j] = f2b(y > 0.f ? y : expm1f(y));
  }
  *(u16x4*)(emb + idx) = o;
}

// ------------ final aggregation: 4 nodes/block, 16 edge-lanes/head, f32x4 zl --------
__global__ __launch_bounds__(256) void finagg_kernel(
    const float* __restrict__ zl, const float* __restrict__ zr,
    const int* __restrict__ rowptr, const int* __restrict__ col,
    const void* fatt, const void* fbconv, const int* flags,
    const float* __restrict__ lp5, void* outv) {
  int node = blockIdx.x * 4 + (threadIdx.x >> 6);   // NN % 4 == 0, grid = NN/4
  int lane = threadIdx.x & 63;
  int bf = flags[0];
  int h = lane >> 4, sub = lane & 15;

  const float* zrp = zr + node * 32 + h * 8;        // 16B-aligned by layout
  f32x4 zr4 = *(const f32x4*)zrp;
  float zrv[5] = {zr4.x, zr4.y, zr4.z, zr4.w, zrp[4]};
  float atv[5];
  #pragma unroll
  for (int c = 0; c < 5; ++c) atv[c] = ldf(fatt, h * 5 + c, bf);

  float l = 0.f, acc[5] = {0.f, 0.f, 0.f, 0.f, 0.f};
  int e0 = rowptr[node], e1 = rowptr[node + 1];
  for (int e = e0 + sub; e < e1; e += 16) {
    int src = col[e];
    const float* zs = zl + src * 32 + h * 8;        // 16B-aligned
    f32x4 z4 = *(const f32x4*)zs;
    float z4s = zs[4];
    float zlv[5] = {z4.x, z4.y, z4.z, z4.w, z4s};
    float s = 0.f;
    #pragma unroll
    for (int c = 0; c < 5; ++c) s += atv[c] * lrelu(zlv[c] + zrv[c]);
    float pz = cexp(s);
    l += pz;
    #pragma unroll
    for (int c = 0; c < 5; ++c) acc[c] += pz * zlv[c];
  }
  #pragma unroll
  for (int off = 1; off < 16; off <<= 1) {
    l += __shfl_xor(l, off);
    #pragma unroll
    for (int c = 0; c < 5; ++c) acc[c] += __shfl_xor(acc[c], off);
  }
  float inv = 1.f / (l + 1e-16f);
  float v[5];
  #pragma unroll
  for (int c = 0; c < 5; ++c) {
    float tv = acc[c] * inv;
    tv += __shfl_xor(tv, 16);
    tv += __shfl_xor(tv, 32);
    v[c] = tv * 0.25f;
  }
  if (lane == 0) {
    float mx = -3.0e38f;
    #pragma unroll
    for (int c = 0; c < 5; ++c) {
      v[c] += ldf(fbconv, c, bf) + lp5[node * 8 + c];
      mx = fmaxf(mx, v[c]);
    }
    float se = 0.f;
    #pragma unroll
    for (int c = 0; c < 5; ++c) se += __expf(v[c] - mx);
    float lse = mx + __logf(se);
    #pragma unroll
    for (int c = 0; c < 5; ++c) {
      float r = v[c] - lse;
      if (bf) ((u16*)outv)[node * 5 + c] = f2b(r);
      else    ((float*)outv)[node * 5 + c] = r;
    }
  }
}

extern "C" void kernel_launch(void* const* d_in, const int* in_sizes, int n_in,
                              void* d_out, int out_size, void* d_ws, size_t ws_size,
                              hipStream_t stream) {
  (void)in_sizes; (void)n_in; (void)out_size; (void)ws_size;
  const void* x     = d_in[0];
  const void* ei    = d_in[1];
  const void* Wl    = d_in[2];
  const void* Wr    = d_in[3];
  const void* att   = d_in[4];
  const void* bconv = d_in[5];
  const void* Wlin  = d_in[6];
  const void* blin  = d_in[7];
  const void* gnw   = d_in[8];
  const void* gnb   = d_in[9];
  const void* gnms  = d_in[10];
  const void* fWl   = d_in[11];
  const void* fWr   = d_in[12];
  const void* fatt  = d_in[13];
  const void* fbc   = d_in[14];
  const void* fWlin = d_in[15];
  const void* fblin = d_in[16];

  char* p = (char*)d_ws;
  auto take = [&](size_t bytes) {
    char* r = p;
    p += (bytes + 511) & ~(size_t)511;
    return r;
  };
  int* flags   = (int*)take(512);
  int* rowptr  = (int*)take((NN + 1) * sizeof(int));
  int* cnt     = (int*)take(NN * sizeof(int));
  int* colx    = (int*)take(EE * sizeof(int));
  int* bsum    = (int*)take(256 * sizeof(int));
  int* boff    = (int*)take(256 * sizeof(int));
  u16* wpack   = (u16*)take((size_t)6 * 65536 * sizeof(u16));
  u16* fwp     = (u16*)take((size_t)32 * 48 * 8 * sizeof(u16));
  float* sums  = (float*)take(512 * sizeof(float));
  // unionA: xb (layer-1 GEMM input) -> cpart bf16 (agg out) -> zl/zr (padded 32) /lp5 (8).
  char* unionA = take((size_t)NN * DD * 4);
  u16* xb      = (u16*)unionA;
  u16* cpart   = (u16*)unionA;
  float* zl    = (float*)unionA;
  float* zr    = (float*)(unionA + (size_t)NN * 32 * 4);
  float* lp5   = (float*)(unionA + (size_t)NN * 64 * 4);
  u16* xl      = (u16*)take((size_t)NN * DD * 2);
  u16* xr      = (u16*)take((size_t)NN * DD * 2);
  u16* lp      = (u16*)take((size_t)NN * DD * 2);
  u16* emb     = (u16*)take((size_t)NN * DD * 2);

  init_kernel<<<dim3(NB), dim3(256), 0, stream>>>(x, ei, flags, cnt);
  hist_kernel<<<dim3((EE + 255) / 256), dim3(256), 0, stream>>>(ei, flags, cnt);
  bsum_kernel<<<dim3(NB), dim3(256), 0, stream>>>(cnt, bsum);
  bscan_kernel<<<dim3(1), dim3(256), 0, stream>>>(bsum, boff);
  bwrite_kernel<<<dim3(NB), dim3(256), 0, stream>>>(cnt, boff, rowptr);
  fill_kernel<<<dim3((EE + 255) / 256), dim3(256), 0, stream>>>(ei, flags, rowptr, cnt, colx);
  prep_kernel<<<dim3(1584 + NN * DD / 1024), dim3(256), 0, stream>>>(
      Wl, Wr, Wlin, fWl, fWr, fWlin, x, flags, wpack, fwp, xb);

  const u16* layerin = xb;
  for (int i = 0; i < 2; ++i) {
    gemm_kernel<<<dim3((NN + 63) / 64, 2), dim3(256), 0, stream>>>(
        layerin, wpack + (size_t)i * 3 * 65536, blin, flags, i, sums, xl, xr, lp, NN);
    agg_kernel<<<dim3(NN / 4), dim3(256), 0, stream>>>(xl, xr, rowptr, colx, att, bconv,
                                                       flags, i, cpart);
    stats_kernel<<<dim3(500), dim3(256), 0, stream>>>(cpart, sums);
    norm_kernel<<<dim3(NN / 4), dim3(256), 0, stream>>>(cpart, lp, gnw, gnb, gnms, flags, i,
                                                        sums, emb);
    layerin = emb;
  }
  fgemm_kernel<<<dim3((NN + 63) / 64), dim3(256), 0, stream>>>(emb, fwp, fblin, flags,
                                                               zl, zr, lp5, NN);
  finagg_kernel<<<dim3(NN / 4), dim3(256), 0, stream>>>(zl, zr, rowptr, colx, fatt, fbc,
                                                        flags, lp5, d_out);
}

// Round 4
// 637.435 us; speedup vs baseline: 1.0861x; 1.0292x over previous
//
#include <hip/hip_runtime.h>

#define NN 50000
#define EE 800000
#define DD 256
#define NB 196   // ceil(NN/256)

typedef unsigned short u16;
typedef unsigned int u32;

typedef __attribute__((ext_vector_type(8))) short short8;
typedef __attribute__((ext_vector_type(4))) float f32x4;
typedef __attribute__((ext_vector_type(4))) unsigned short u16x4;
typedef __attribute__((ext_vector_type(4))) int i32x4;

__device__ __forceinline__ float b2f(u16 u) {
  union { u32 i; float f; } c; c.i = ((u32)u) << 16; return c.f;
}
__device__ __forceinline__ u16 f2b(float f) {
  union { float f; u32 i; } c; c.f = f;
  u32 u = c.i;
  return (u16)((u + 0x7fffu + ((u >> 16) & 1u)) >> 16);
}
// slope<1: lrelu(x) == max(x, 0.2x) exactly
__device__ __forceinline__ float lrelu(float x) { return fmaxf(x, 0.2f * x); }
__device__ __forceinline__ float ldf(const void* p, int i, int bf) {
  return bf ? b2f(((const u16*)p)[i]) : ((const float*)p)[i];
}
__device__ __forceinline__ int lde(const void* ei, int idx, int m64) {
  int v = m64 ? (int)((const long long*)ei)[idx] : ((const int*)ei)[idx];
  return v < 0 ? 0 : (v >= NN ? NN - 1 : v);
}
// softmax without online max: shift-invariant, scores bounded -> exact vs ref
__device__ __forceinline__ float cexp(float s) {
  return __expf(__builtin_amdgcn_fmed3f(s, -60.f, 60.f));
}

// ---- DPP 16-lane butterfly add: bit-identical to shfl_xor{1,2,4,8} chain ----
template <int CTRL>
__device__ __forceinline__ float dpp_add(float s) {
  union { float f; int i; } a, b;
  a.f = s;
  b.i = __builtin_amdgcn_update_dpp(0, a.i, CTRL, 0xf, 0xf, true);
  return s + b.f;
}
__device__ __forceinline__ float row16_allsum(float s) {
  s = dpp_add<0xB1>(s);
  s = dpp_add<0x4E>(s);
  s = dpp_add<0x141>(s);
  s = dpp_add<0x140>(s);
  return s;
}

// ---- async global->LDS (16B/lane, dest = wave-uniform base + lane*16) ----
__device__ __forceinline__ void gload_lds16(const void* g, void* l) {
  __builtin_amdgcn_global_load_lds(
      (const __attribute__((address_space(1))) void*)g,
      (__attribute__((address_space(3))) void*)l, 16, 0, 0);
}

// ---------------- init: zero cnt + dtype detection (block 0, wave 0) ----------------
__global__ __launch_bounds__(256) void init_kernel(const void* x, const void* ei,
                                                   int* flags, int* cnt) {
  int i = blockIdx.x * 256 + threadIdx.x;
  if (i < NN) cnt[i] = 0;
  if (blockIdx.x == 0 && threadIdx.x < 64) {
    int lane = threadIdx.x;
    const u16* xw = (const u16*)x;
    int c = 0;
    for (int k = lane; k < 512; k += 64) {
      u16 w = xw[k];
      int e = (w >> 7) & 0xFF;
      if ((e >= 107 && e <= 147) || (w & 0x7FFF) == 0) ++c;
    }
    const u32* ew = (const u32*)ei;
    int zc = 0;
    for (int k = 1 + 2 * lane; k < 1024; k += 128)
      if (ew[k] == 0) ++zc;
    #pragma unroll
    for (int off = 1; off < 64; off <<= 1) {
      c += __shfl_xor(c, off);
      zc += __shfl_xor(zc, off);
    }
    if (lane == 0) {
      flags[0] = (c >= 440) ? 1 : 0;
      flags[1] = (zc >= 400) ? 1 : 0;
    }
  }
}

// ---------------- CSR build ----------------
__global__ void hist_kernel(const void* ei, const int* flags, int* cnt) {
  int e = blockIdx.x * 256 + threadIdx.x;
  if (e < EE) atomicAdd(&cnt[lde(ei, EE + e, flags[1])], 1);
}

// -------- parallel 3-phase exclusive scan of deg[NN] -> rowptr[NN+1] --------
__global__ __launch_bounds__(256) void bsum_kernel(const int* __restrict__ deg,
                                                   int* __restrict__ bsum) {
  int i = blockIdx.x * 256 + threadIdx.x;
  int v = (i < NN) ? deg[i] : 0;
  #pragma unroll
  for (int off = 1; off < 64; off <<= 1) v += __shfl_xor(v, off);
  __shared__ int ws[4];
  int lane = threadIdx.x & 63, wid = threadIdx.x >> 6;
  if (lane == 0) ws[wid] = v;
  __syncthreads();
  if (threadIdx.x == 0) bsum[blockIdx.x] = ws[0] + ws[1] + ws[2] + ws[3];
}

__global__ __launch_bounds__(256) void bscan_kernel(const int* __restrict__ bsum,
                                                    int* __restrict__ boff) {
  int t = threadIdx.x;
  int v = (t < NB) ? bsum[t] : 0;
  int iv = v;
  int lane = t & 63, wid = t >> 6;
  #pragma unroll
  for (int off = 1; off < 64; off <<= 1) {
    int u = __shfl_up(iv, off);
    if (lane >= off) iv += u;
  }
  __shared__ int ws[4];
  if (lane == 63) ws[wid] = iv;
  __syncthreads();
  int add = 0;
  for (int w = 0; w < wid; ++w) add += ws[w];
  if (t < NB) boff[t] = iv - v + add;
}

__global__ __launch_bounds__(256) void bwrite_kernel(const int* __restrict__ deg,
                                                     const int* __restrict__ boff,
                                                     int* __restrict__ rowptr) {
  int i = blockIdx.x * 256 + threadIdx.x;
  int v = (i < NN) ? deg[i] : 0;
  int iv = v;
  int lane = threadIdx.x & 63, wid = threadIdx.x >> 6;
  #pragma unroll
  for (int off = 1; off < 64; off <<= 1) {
    int u = __shfl_up(iv, off);
    if (lane >= off) iv += u;
  }
  __shared__ int ws[4];
  if (lane == 63) ws[wid] = iv;
  __syncthreads();
  int add = boff[blockIdx.x];
  for (int w = 0; w < wid; ++w) add += ws[w];
  if (i <= NN) rowptr[i] = iv - v + add;
}

// uses hist counts (cnt[dst]=deg) via atomicSub -> no second memset needed
__global__ void fill_kernel(const void* ei, const int* flags, const int* __restrict__ rowptr,
                            int* __restrict__ cnt, int* __restrict__ col) {
  int e = blockIdx.x * 256 + threadIdx.x;
  if (e < EE) {
    int m64 = flags[1];
    int dst = lde(ei, EE + e, m64);
    int old = atomicSub(&cnt[dst], 1);
    int pos = rowptr[dst] + old - 1;
    if (pos >= 0 && pos < EE) col[pos] = lde(ei, e, m64);
  }
}

// -------- prep: weight pack (MFMA B-frag order) + final-weight pack + x->bf16 --------
// grid 14084: [0,1536) pack wpack, [1536,1584) pack fwp, [1584,14084) convert x.
__global__ __launch_bounds__(256) void prep_kernel(
    const void* Wl, const void* Wr, const void* Wlin,
    const void* fWl, const void* fWr, const void* fWlin,
    const void* x, const int* flags, u16* wpack, u16* fwp, u16* xb) {
  int bf = flags[0];
  int bid = blockIdx.x;
  if (bid < 1536) {
    int idx = bid * 256 + threadIdx.x;
    int m = idx >> 16, e = idx & 65535;
    int layer = (m >= 3) ? 1 : 0, sel = m - layer * 3;
    const void* src = (sel == 0 ? Wl : (sel == 1 ? Wr : Wlin));
    int k = e >> 8, n = e & 255;
    wpack[(m << 16) + ((((k >> 3) << 8) + n) << 3) + (k & 7)] =
        f2b(ldf(src, layer * 65536 + e, bf));
  } else if (bid < 1584) {
    int idx = (bid - 1536) * 256 + threadIdx.x;
    int j = idx & 7;
    int col = (idx >> 3) % 48;
    int kk = idx / (48 * 8);
    int k = kk * 8 + j;
    float v = 0.f;
    if (col < 20)      v = ldf(fWl, k * 20 + col, bf);
    else if (col < 40) v = ldf(fWr, k * 20 + (col - 20), bf);
    else if (col < 45) v = ldf(fWlin, k * 5 + (col - 40), bf);
    fwp[idx] = f2b(v);
  } else {
    int base = (bid - 1584) * 1024 + threadIdx.x * 4;
    if (bf) {
      *(u16x4*)(xb + base) = *(const u16x4*)((const u16*)x + base);
    } else {
      f32x4 s = *(const f32x4*)((const float*)x + base);
      u16x4 o;
      #pragma unroll
      for (int j = 0; j < 4; ++j) o[j] = f2b(s[j]);
      *(u16x4*)(xb + base) = o;
    }
  }
}

// ------- fused GEMM: (M x 256) x (256 x 768), A-resident + LDS-staged B -------------
// Operand-SWAPPED MFMA: D = W_tile^T * X_tile^T. A-frag (weights) comes from LDS
// (lane t = output col, k-run per q); B-frag (x rows) is the register-resident af.
// C/D mapping (col=lane&15 -> node row, row=(lane>>4)*4+reg -> channel) gives each
// lane 4 CONSECUTIVE output channels at one row -> one u16x4 store per ns (was 4x 2B).
__global__ __launch_bounds__(256) void gemm_kernel(
    const u16* __restrict__ A, const u16* __restrict__ wpack, const void* blin,
    const int* flags, int layer, float* __restrict__ sums,
    u16* __restrict__ xl, u16* __restrict__ xr, u16* __restrict__ lp, int M) {
  __shared__ __align__(16) u16 bsh[16384];   // 32 KB: [kk 0..31][col 0..63][j 0..7]
  if (blockIdx.x == 0 && blockIdx.y == 0) {
    sums[threadIdx.x] = 0.f;
    sums[threadIdx.x + 256] = 0.f;
  }
  int wave = threadIdx.x >> 6;
  int lane = threadIdx.x & 63;
  int q = lane >> 4;
  int t = lane & 15;
  int m0 = blockIdx.x * 64 + wave * 16;
  int yh = blockIdx.y;

  int arow = m0 + t;
  if (arow >= M) arow = M - 1;
  const u16* Abase = A + (size_t)arow * DD + q * 8;
  short8 af[8];
  #pragma unroll
  for (int i = 0; i < 8; ++i) af[i] = *(const short8*)(Abase + i * 32);

  int bf = flags[0];
  int m = m0 + t;                 // output row owned by this lane (swapped layout)

  for (int yi = 0; yi < 6; ++yi) {
    int y = yh * 6 + yi;
    int mm = y >> 2;
    int col0 = (y & 3) * 64;
    const u16* wb = wpack + (mm << 16);

    __syncthreads();   // previous iteration's LDS reads complete
    #pragma unroll
    for (int itc = 0; itc < 8; ++itc) {
      int kk = wave + itc * 4;                       // = chunk>>6, uniform per wave
      const u16* gp = wb + (((kk << 8) + col0) << 3) + (lane << 3);
      u16* lb = &bsh[(wave * 64 + itc * 256) << 3];  // wave-uniform base
      gload_lds16(gp, lb);
    }
    __syncthreads();   // drains vmcnt (global_load_lds) before LDS reads

    f32x4 acc[4];
    #pragma unroll
    for (int ns = 0; ns < 4; ++ns) acc[ns] = (f32x4){0.f, 0.f, 0.f, 0.f};

    #pragma unroll
    for (int i = 0; i < 8; ++i) {
      int kk = i * 4 + q;
      const u16* bb = &bsh[(kk << 9) + (t << 3)];
      #pragma unroll
      for (int ns = 0; ns < 4; ++ns) {
        short8 b = *(const short8*)(bb + (ns << 7));
        // swapped: weights as A-operand, x-rows as B-operand
        acc[ns] = __builtin_amdgcn_mfma_f32_16x16x32_bf16(b, af[i], acc[ns], 0, 0, 0);
      }
    }

    u16* dstp = (y < 4) ? xl : (y < 8) ? xr : lp;
    bool isLp = (y >= 8);
    if (m < M) {
      #pragma unroll
      for (int ns = 0; ns < 4; ++ns) {
        int c0 = col0 + ns * 16 + q * 4;
        u16x4 w;
        #pragma unroll
        for (int r = 0; r < 4; ++r) {
          float bias = isLp ? ldf(blin, layer * 256 + c0 + r, bf) : 0.f;
          w[r] = f2b(acc[ns][r] + bias);
        }
        *(u16x4*)(dstp + (size_t)m * DD + c0) = w;
      }
    }
  }
}

// ------ final GEMM via MFMA: emb @ [fWl|fWr|fWlin] -> zl/zr padded [N][32], lp [N][8]
__global__ __launch_bounds__(256) void fgemm_kernel(
    const u16* __restrict__ A, const u16* __restrict__ fwp, const void* fblin,
    const int* flags, float* __restrict__ zl, float* __restrict__ zr,
    float* __restrict__ lp5, int M) {
  int wave = threadIdx.x >> 6;
  int lane = threadIdx.x & 63;
  int q = lane >> 4;
  int t = lane & 15;
  int m0 = blockIdx.x * 64 + wave * 16;

  f32x4 acc[3];
  #pragma unroll
  for (int ns = 0; ns < 3; ++ns) acc[ns] = (f32x4){0.f, 0.f, 0.f, 0.f};

  int arow = m0 + t;
  if (arow >= M) arow = M - 1;
  const u16* Abase = A + (size_t)arow * DD + q * 8;

  #pragma unroll
  for (int k0 = 0; k0 < DD; k0 += 32) {
    short8 a = *(const short8*)(Abase + k0);
    int kk = (k0 >> 3) + q;
    #pragma unroll
    for (int ns = 0; ns < 3; ++ns) {
      short8 b = *(const short8*)(fwp + (((kk * 48) + ns * 16 + t) << 3));
      acc[ns] = __builtin_amdgcn_mfma_f32_16x16x32_bf16(a, b, acc[ns], 0, 0, 0);
    }
  }

  int bf = flags[0];
  #pragma unroll
  for (int ns = 0; ns < 3; ++ns) {
    int c = ns * 16 + t;
    #pragma unroll
    for (int r = 0; r < 4; ++r) {
      int row = m0 + q * 4 + r;
      if (row < M) {
        float v = acc[ns][r];
        if (c < 20) {
          zl[row * 32 + (c / 5) * 8 + (c % 5)] = v;
        } else if (c < 40) {
          int c2 = c - 20;
          zr[row * 32 + (c2 / 5) * 8 + (c2 % 5)] = v;
        } else if (c < 45) {
          lp5[row * 8 + (c - 40)] = v + ldf(fblin, c - 40, bf);
        }
      }
    }
  }
}

// ------- GATv2 aggregation: 4 nodes/block (wave=node), scalar math + DPP reduce -----
__device__ __forceinline__ void edge_step(u16x4 s4, const float* xrv, const float* atv,
                                          float& l, float* acc) {
  float x0 = b2f(s4[0]), x1 = b2f(s4[1]), x2 = b2f(s4[2]), x3 = b2f(s4[3]);
  float sp = atv[0] * lrelu(x0 + xrv[0]) + atv[1] * lrelu(x1 + xrv[1]) +
             atv[2] * lrelu(x2 + xrv[2]) + atv[3] * lrelu(x3 + xrv[3]);
  sp = row16_allsum(sp);        // bit-identical to shfl_xor{1,2,4,8}, zero DS ops
  float pz = cexp(sp);
  l += pz;
  acc[0] += pz * x0;
  acc[1] += pz * x1;
  acc[2] += pz * x2;
  acc[3] += pz * x3;
}

__global__ __launch_bounds__(256) void agg_kernel(
    const u16* __restrict__ xl, const u16* __restrict__ xr,
    const int* __restrict__ rowptr, const int* __restrict__ col,
    const void* att, const void* bconv, const int* flags, int layer,
    u16* __restrict__ cpart) {
  int wave = threadIdx.x >> 6;
  int node = blockIdx.x * 4 + wave;   // NN % 4 == 0, grid = NN/4
  int lane = threadIdx.x & 63;
  int h = lane >> 4;
  int cb = (lane & 15) * 4;
  int base = h * 64 + cb;
  int bf = flags[0];

  u16x4 r4 = *(const u16x4*)(xr + (size_t)node * DD + base);
  float xrv[4], atv[4];
  #pragma unroll
  for (int j = 0; j < 4; ++j) {
    xrv[j] = b2f(r4[j]);
    atv[j] = ldf(att, layer * 256 + base + j, bf);
  }

  float l = 0.f;
  float acc[4] = {0.f, 0.f, 0.f, 0.f};
  int e0 = rowptr[node], e1 = rowptr[node + 1];
  const char* xlb = (const char*)xl;          // SGPR base; 32-bit voffset per gather
  u32 baseb = (u32)(base << 1);

  int e = e0;
  for (; e < e1 && (e & 3); ++e) {            // align to 16B for int4 col loads
    u16x4 v = *(const u16x4*)(xlb + (((u32)col[e] << 9) + baseb));
    edge_step(v, xrv, atv, l, acc);
  }
  int nq = (e1 - e) >> 2;
  if (nq > 0) {
    i32x4 cq = *(const i32x4*)(col + e);      // software-pipelined col prefetch
    for (int g = 0; g < nq; ++g) {
      i32x4 nx = (g + 1 < nq) ? *(const i32x4*)(col + e + 4) : cq;
      u16x4 v0 = *(const u16x4*)(xlb + (((u32)cq.x << 9) + baseb));
      u16x4 v1 = *(const u16x4*)(xlb + (((u32)cq.y << 9) + baseb));
      u16x4 v2 = *(const u16x4*)(xlb + (((u32)cq.z << 9) + baseb));
      u16x4 v3 = *(const u16x4*)(xlb + (((u32)cq.w << 9) + baseb));
      edge_step(v0, xrv, atv, l, acc);
      edge_step(v1, xrv, atv, l, acc);
      edge_step(v2, xrv, atv, l, acc);
      edge_step(v3, xrv, atv, l, acc);
      cq = nx;
      e += 4;
    }
  }
  for (; e < e1; ++e) {
    u16x4 v = *(const u16x4*)(xlb + (((u32)col[e] << 9) + baseb));
    edge_step(v, xrv, atv, l, acc);
  }

  float inv = 1.f / (l + 1e-16f);
  u16x4 outw;
  #pragma unroll
  for (int j = 0; j < 4; ++j)
    outw[j] = f2b(acc[j] * inv + ldf(bconv, layer * 256 + base + j, bf));
  *(u16x4*)(cpart + (size_t)node * DD + base) = outw;
}

// ---------------- GraphNorm stats (bf16 input) ----------------
__global__ __launch_bounds__(256) void stats_kernel(const u16* __restrict__ cpart,
                                                    float* __restrict__ sums) {
  int ch = threadIdx.x;
  int n0 = blockIdx.x * 100, n1 = n0 + 100;
  float s = 0.f, s2 = 0.f;
  for (int n = n0; n < n1; ++n) {
    float x = b2f(cpart[(size_t)n * DD + ch]);
    s += x; s2 += x * x;
  }
  atomicAdd(&sums[ch], s);
  atomicAdd(&sums[256 + ch], s2);
}

// ---------------- GraphNorm + skip + ELU (bf16 cpart, u16x4-vectorized) -------------
__global__ __launch_bounds__(256) void norm_kernel(
    const u16* __restrict__ cpart, const u16* __restrict__ lp,
    const void* gw, const void* gb, const void* gms, const int* flags, int layer,
    const float* __restrict__ sums, u16* __restrict__ emb) {
  int t = threadIdx.x;
  int node = blockIdx.x * 4 + (t >> 6);     // NN % 4 == 0, grid = NN/4
  int c4 = (t & 63) * 4;
  int bf = flags[0];
  size_t idx = (size_t)node * DD + c4;
  const float invN = 1.f / (float)NN;
  u16x4 cp = *(const u16x4*)(cpart + idx);
  u16x4 lv = *(const u16x4*)(lp + idx);
  u16x4 o;
  #pragma unroll
  for (int j = 0; j < 4; ++j) {
    int ch = c4 + j;
    float mean = sums[ch] * invN;
    float ex2 = sums[256 + ch] * invN;
    float mm = mean * ldf(gms, layer * 256 + ch, bf);
    float var = ex2 - 2.f * mm * mean + mm * mm;
    float x = b2f(cp[j]);
    float y = ldf(gw, layer * 256 + ch, bf) * (x - mm) * rsqrtf(fmaxf(var, 0.f) + 1e-5f) +
              ldf(gb, layer * 256 + ch, bf) + b2f(lv[j]);
    o[j] = f2b(y > 0.f ? y : expm1f(y));
  }
  *(u16x4*)(emb + idx) = o;
}

// ------------ final aggregation: 4 nodes/block, 16 edge-lanes/head, f32x4 zl --------
__global__ __launch_bounds__(256) void finagg_kernel(
    const float* __restrict__ zl, const float* __restrict__ zr,
    const int* __restrict__ rowptr, const int* __restrict__ col,
    const void* fatt, const void* fbconv, const int* flags,
    const float* __restrict__ lp5, void* outv) {
  int node = blockIdx.x * 4 + (threadIdx.x >> 6);   // NN % 4 == 0, grid = NN/4
  int lane = threadIdx.x & 63;
  int bf = flags[0];
  int h = lane >> 4, sub = lane & 15;

  const float* zrp = zr + node * 32 + h * 8;        // 16B-aligned by layout
  f32x4 zr4 = *(const f32x4*)zrp;
  float zrv[5] = {zr4.x, zr4.y, zr4.z, zr4.w, zrp[4]};
  float atv[5];
  #pragma unroll
  for (int c = 0; c < 5; ++c) atv[c] = ldf(fatt, h * 5 + c, bf);

  float l = 0.f, acc[5] = {0.f, 0.f, 0.f, 0.f, 0.f};
  int e0 = rowptr[node], e1 = rowptr[node + 1];
  for (int e = e0 + sub; e < e1; e += 16) {
    int src = col[e];
    const float* zs = zl + src * 32 + h * 8;        // 16B-aligned
    f32x4 z4 = *(const f32x4*)zs;
    float z4s = zs[4];
    float zlv[5] = {z4.x, z4.y, z4.z, z4.w, z4s};
    float s = 0.f;
    #pragma unroll
    for (int c = 0; c < 5; ++c) s += atv[c] * lrelu(zlv[c] + zrv[c]);
    float pz = cexp(s);
    l += pz;
    #pragma unroll
    for (int c = 0; c < 5; ++c) acc[c] += pz * zlv[c];
  }
  #pragma unroll
  for (int off = 1; off < 16; off <<= 1) {
    l += __shfl_xor(l, off);
    #pragma unroll
    for (int c = 0; c < 5; ++c) acc[c] += __shfl_xor(acc[c], off);
  }
  float inv = 1.f / (l + 1e-16f);
  float v[5];
  #pragma unroll
  for (int c = 0; c < 5; ++c) {
    float tv = acc[c] * inv;
    tv += __shfl_xor(tv, 16);
    tv += __shfl_xor(tv, 32);
    v[c] = tv * 0.25f;
  }
  if (lane == 0) {
    float mx = -3.0e38f;
    #pragma unroll
    for (int c = 0; c < 5; ++c) {
      v[c] += ldf(fbconv, c, bf) + lp5[node * 8 + c];
      mx = fmaxf(mx, v[c]);
    }
    float se = 0.f;
    #pragma unroll
    for (int c = 0; c < 5; ++c) se += __expf(v[c] - mx);
    float lse = mx + __logf(se);
    #pragma unroll
    for (int c = 0; c < 5; ++c) {
      float r = v[c] - lse;
      if (bf) ((u16*)outv)[node * 5 + c] = f2b(r);
      else    ((float*)outv)[node * 5 + c] = r;
    }
  }
}

extern "C" void kernel_launch(void* const* d_in, const int* in_sizes, int n_in,
                              void* d_out, int out_size, void* d_ws, size_t ws_size,
                              hipStream_t stream) {
  (void)in_sizes; (void)n_in; (void)out_size; (void)ws_size;
  const void* x     = d_in[0];
  const void* ei    = d_in[1];
  const void* Wl    = d_in[2];
  const void* Wr    = d_in[3];
  const void* att   = d_in[4];
  const void* bconv = d_in[5];
  const void* Wlin  = d_in[6];
  const void* blin  = d_in[7];
  const void* gnw   = d_in[8];
  const void* gnb   = d_in[9];
  const void* gnms  = d_in[10];
  const void* fWl   = d_in[11];
  const void* fWr   = d_in[12];
  const void* fatt  = d_in[13];
  const void* fbc   = d_in[14];
  const void* fWlin = d_in[15];
  const void* fblin = d_in[16];

  char* p = (char*)d_ws;
  auto take = [&](size_t bytes) {
    char* r = p;
    p += (bytes + 511) & ~(size_t)511;
    return r;
  };
  int* flags   = (int*)take(512);
  int* rowptr  = (int*)take((NN + 1) * sizeof(int));
  int* cnt     = (int*)take(NN * sizeof(int));
  int* colx    = (int*)take(EE * sizeof(int));
  int* bsum    = (int*)take(256 * sizeof(int));
  int* boff    = (int*)take(256 * sizeof(int));
  u16* wpack   = (u16*)take((size_t)6 * 65536 * sizeof(u16));
  u16* fwp     = (u16*)take((size_t)32 * 48 * 8 * sizeof(u16));
  float* sums  = (float*)take(512 * sizeof(float));
  // unionA: xb (layer-1 GEMM input) -> cpart bf16 (agg out) -> zl/zr (padded 32) /lp5 (8).
  char* unionA = take((size_t)NN * DD * 4);
  u16* xb      = (u16*)unionA;
  u16* cpart   = (u16*)unionA;
  float* zl    = (float*)unionA;
  float* zr    = (float*)(unionA + (size_t)NN * 32 * 4);
  float* lp5   = (float*)(unionA + (size_t)NN * 64 * 4);
  u16* xl      = (u16*)take((size_t)NN * DD * 2);
  u16* xr      = (u16*)take((size_t)NN * DD * 2);
  u16* lp      = (u16*)take((size_t)NN * DD * 2);
  u16* emb     = (u16*)take((size_t)NN * DD * 2);

  init_kernel<<<dim3(NB), dim3(256), 0, stream>>>(x, ei, flags, cnt);
  hist_kernel<<<dim3((EE + 255) / 256), dim3(256), 0, stream>>>(ei, flags, cnt);
  bsum_kernel<<<dim3(NB), dim3(256), 0, stream>>>(cnt, bsum);
  bscan_kernel<<<dim3(1), dim3(256), 0, stream>>>(bsum, boff);
  bwrite_kernel<<<dim3(NB), dim3(256), 0, stream>>>(cnt, boff, rowptr);
  fill_kernel<<<dim3((EE + 255) / 256), dim3(256), 0, stream>>>(ei, flags, rowptr, cnt, colx);
  prep_kernel<<<dim3(1584 + NN * DD / 1024), dim3(256), 0, stream>>>(
      Wl, Wr, Wlin, fWl, fWr, fWlin, x, flags, wpack, fwp, xb);

  const u16* layerin = xb;
  for (int i = 0; i < 2; ++i) {
    gemm_kernel<<<dim3((NN + 63) / 64, 2), dim3(256), 0, stream>>>(
        layerin, wpack + (size_t)i * 3 * 65536, blin, flags, i, sums, xl, xr, lp, NN);
    agg_kernel<<<dim3(NN / 4), dim3(256), 0, stream>>>(xl, xr, rowptr, colx, att, bconv,
                                                       flags, i, cpart);
    stats_kernel<<<dim3(500), dim3(256), 0, stream>>>(cpart, sums);
    norm_kernel<<<dim3(NN / 4), dim3(256), 0, stream>>>(cpart, lp, gnw, gnb, gnms, flags, i,
                                                        sums, emb);
    layerin = emb;
  }
  fgemm_kernel<<<dim3((NN + 63) / 64), dim3(256), 0, stream>>>(emb, fwp, fblin, flags,
                                                               zl, zr, lp5, NN);
  finagg_kernel<<<dim3(NN / 4), dim3(256), 0, stream>>>(zl, zr, rowptr, colx, fatt, fbc,
                                                        flags, lp5, d_out);
}

// Round 5
// 547.376 us; speedup vs baseline: 1.2648x; 1.1645x over previous
//
#include <hip/hip_runtime.h>

#define NN 50000
#define EE 800000
#define DD 256
#define NB 196   // ceil(NN/256)

typedef unsigned short u16;
typedef unsigned int u32;

typedef __attribute__((ext_vector_type(8))) short short8;
typedef __attribute__((ext_vector_type(4))) float f32x4;
typedef __attribute__((ext_vector_type(4))) unsigned short u16x4;
typedef __attribute__((ext_vector_type(4))) int i32x4;

__device__ __forceinline__ float b2f(u16 u) {
  union { u32 i; float f; } c; c.i = ((u32)u) << 16; return c.f;
}
__device__ __forceinline__ u16 f2b(float f) {
  union { float f; u32 i; } c; c.f = f;
  u32 u = c.i;
  return (u16)((u + 0x7fffu + ((u >> 16) & 1u)) >> 16);
}
// slope<1: lrelu(x) == max(x, 0.2x) exactly
__device__ __forceinline__ float lrelu(float x) { return fmaxf(x, 0.2f * x); }
__device__ __forceinline__ float ldf(const void* p, int i, int bf) {
  return bf ? b2f(((const u16*)p)[i]) : ((const float*)p)[i];
}
__device__ __forceinline__ int lde(const void* ei, int idx, int m64) {
  int v = m64 ? (int)((const long long*)ei)[idx] : ((const int*)ei)[idx];
  return v < 0 ? 0 : (v >= NN ? NN - 1 : v);
}
// softmax without online max: shift-invariant, scores bounded -> exact vs ref
__device__ __forceinline__ float cexp(float s) {
  return __expf(__builtin_amdgcn_fmed3f(s, -60.f, 60.f));
}

// ---- DPP 16-lane butterfly add: bit-identical to shfl_xor{1,2,4,8} chain ----
template <int CTRL>
__device__ __forceinline__ float dpp_add(float s) {
  union { float f; int i; } a, b;
  a.f = s;
  b.i = __builtin_amdgcn_update_dpp(0, a.i, CTRL, 0xf, 0xf, true);
  return s + b.f;
}
__device__ __forceinline__ float row16_allsum(float s) {
  s = dpp_add<0xB1>(s);
  s = dpp_add<0x4E>(s);
  s = dpp_add<0x141>(s);
  s = dpp_add<0x140>(s);
  return s;
}

// ---- async global->LDS (16B/lane, dest = wave-uniform base + lane*16) ----
__device__ __forceinline__ void gload_lds16(const void* g, void* l) {
  __builtin_amdgcn_global_load_lds(
      (const __attribute__((address_space(1))) void*)g,
      (__attribute__((address_space(3))) void*)l, 16, 0, 0);
}

// ------- init: zero cnt + zero sums (both layers) + dtype detection ----------------
__global__ __launch_bounds__(256) void init_kernel(const void* x, const void* ei,
                                                   int* flags, int* cnt,
                                                   float* sums) {
  int i = blockIdx.x * 256 + threadIdx.x;
  if (i < NN) cnt[i] = 0;
  if (blockIdx.x == 1) {
    #pragma unroll
    for (int j = 0; j < 4; ++j) sums[threadIdx.x + j * 256] = 0.f;
  }
  if (blockIdx.x == 0 && threadIdx.x < 64) {
    int lane = threadIdx.x;
    const u16* xw = (const u16*)x;
    int c = 0;
    for (int k = lane; k < 512; k += 64) {
      u16 w = xw[k];
      int e = (w >> 7) & 0xFF;
      if ((e >= 107 && e <= 147) || (w & 0x7FFF) == 0) ++c;
    }
    const u32* ew = (const u32*)ei;
    int zc = 0;
    for (int k = 1 + 2 * lane; k < 1024; k += 128)
      if (ew[k] == 0) ++zc;
    #pragma unroll
    for (int off = 1; off < 64; off <<= 1) {
      c += __shfl_xor(c, off);
      zc += __shfl_xor(zc, off);
    }
    if (lane == 0) {
      flags[0] = (c >= 440) ? 1 : 0;
      flags[1] = (zc >= 400) ? 1 : 0;
    }
  }
}

// ---------------- CSR build ----------------
__global__ void hist_kernel(const void* ei, const int* flags, int* cnt) {
  int e = blockIdx.x * 256 + threadIdx.x;
  if (e < EE) atomicAdd(&cnt[lde(ei, EE + e, flags[1])], 1);
}

// -------- parallel 3-phase exclusive scan of deg[NN] -> rowptr[NN+1] --------
__global__ __launch_bounds__(256) void bsum_kernel(const int* __restrict__ deg,
                                                   int* __restrict__ bsum) {
  int i = blockIdx.x * 256 + threadIdx.x;
  int v = (i < NN) ? deg[i] : 0;
  #pragma unroll
  for (int off = 1; off < 64; off <<= 1) v += __shfl_xor(v, off);
  __shared__ int ws[4];
  int lane = threadIdx.x & 63, wid = threadIdx.x >> 6;
  if (lane == 0) ws[wid] = v;
  __syncthreads();
  if (threadIdx.x == 0) bsum[blockIdx.x] = ws[0] + ws[1] + ws[2] + ws[3];
}

__global__ __launch_bounds__(256) void bscan_kernel(const int* __restrict__ bsum,
                                                    int* __restrict__ boff) {
  int t = threadIdx.x;
  int v = (t < NB) ? bsum[t] : 0;
  int iv = v;
  int lane = t & 63, wid = t >> 6;
  #pragma unroll
  for (int off = 1; off < 64; off <<= 1) {
    int u = __shfl_up(iv, off);
    if (lane >= off) iv += u;
  }
  __shared__ int ws[4];
  if (lane == 63) ws[wid] = iv;
  __syncthreads();
  int add = 0;
  for (int w = 0; w < wid; ++w) add += ws[w];
  if (t < NB) boff[t] = iv - v + add;
}

__global__ __launch_bounds__(256) void bwrite_kernel(const int* __restrict__ deg,
                                                     const int* __restrict__ boff,
                                                     int* __restrict__ rowptr) {
  int i = blockIdx.x * 256 + threadIdx.x;
  int v = (i < NN) ? deg[i] : 0;
  int iv = v;
  int lane = threadIdx.x & 63, wid = threadIdx.x >> 6;
  #pragma unroll
  for (int off = 1; off < 64; off <<= 1) {
    int u = __shfl_up(iv, off);
    if (lane >= off) iv += u;
  }
  __shared__ int ws[4];
  if (lane == 63) ws[wid] = iv;
  __syncthreads();
  int add = boff[blockIdx.x];
  for (int w = 0; w < wid; ++w) add += ws[w];
  if (i <= NN) rowptr[i] = iv - v + add;
}

// uses hist counts (cnt[dst]=deg) via atomicSub -> no second memset needed
__global__ void fill_kernel(const void* ei, const int* flags, const int* __restrict__ rowptr,
                            int* __restrict__ cnt, int* __restrict__ col) {
  int e = blockIdx.x * 256 + threadIdx.x;
  if (e < EE) {
    int m64 = flags[1];
    int dst = lde(ei, EE + e, m64);
    int old = atomicSub(&cnt[dst], 1);
    int pos = rowptr[dst] + old - 1;
    if (pos >= 0 && pos < EE) col[pos] = lde(ei, e, m64);
  }
}

// -------- prep: weight pack (MFMA B-frag order) + final-weight pack + x->bf16 --------
// grid 14084: [0,1536) pack wpack, [1536,1584) pack fwp, [1584,14084) convert x.
__global__ __launch_bounds__(256) void prep_kernel(
    const void* Wl, const void* Wr, const void* Wlin,
    const void* fWl, const void* fWr, const void* fWlin,
    const void* x, const int* flags, u16* wpack, u16* fwp, u16* xb) {
  int bf = flags[0];
  int bid = blockIdx.x;
  if (bid < 1536) {
    int idx = bid * 256 + threadIdx.x;
    int m = idx >> 16, e = idx & 65535;
    int layer = (m >= 3) ? 1 : 0, sel = m - layer * 3;
    const void* src = (sel == 0 ? Wl : (sel == 1 ? Wr : Wlin));
    int k = e >> 8, n = e & 255;
    wpack[(m << 16) + ((((k >> 3) << 8) + n) << 3) + (k & 7)] =
        f2b(ldf(src, layer * 65536 + e, bf));
  } else if (bid < 1584) {
    int idx = (bid - 1536) * 256 + threadIdx.x;
    int j = idx & 7;
    int col = (idx >> 3) % 48;
    int kk = idx / (48 * 8);
    int k = kk * 8 + j;
    float v = 0.f;
    if (col < 20)      v = ldf(fWl, k * 20 + col, bf);
    else if (col < 40) v = ldf(fWr, k * 20 + (col - 20), bf);
    else if (col < 45) v = ldf(fWlin, k * 5 + (col - 40), bf);
    fwp[idx] = f2b(v);
  } else {
    int base = (bid - 1584) * 1024 + threadIdx.x * 4;
    if (bf) {
      *(u16x4*)(xb + base) = *(const u16x4*)((const u16*)x + base);
    } else {
      f32x4 s = *(const f32x4*)((const float*)x + base);
      u16x4 o;
      #pragma unroll
      for (int j = 0; j < 4; ++j) o[j] = f2b(s[j]);
      *(u16x4*)(xb + base) = o;
    }
  }
}

// ------ nprep: GraphNorm stats -> per-channel affine (a,b): y = a*x + b + lp --------
// a = gw * rsqrt(var+eps), b = gb - a*mm. 1 block, 256 threads.
__global__ __launch_bounds__(256) void nprep_kernel(
    const float* __restrict__ sums, const void* gw, const void* gb, const void* gms,
    const int* flags, int layer, float* __restrict__ ab) {
  int ch = threadIdx.x;
  int bf = flags[0];
  const float invN = 1.f / (float)NN;
  float mean = sums[layer * 512 + ch] * invN;
  float ex2 = sums[layer * 512 + 256 + ch] * invN;
  float mm = mean * ldf(gms, layer * 256 + ch, bf);
  float var = ex2 - 2.f * mm * mean + mm * mm;
  float rs = rsqrtf(fmaxf(var, 0.f) + 1e-5f);
  float a = ldf(gw, layer * 256 + ch, bf) * rs;
  float b = ldf(gb, layer * 256 + ch, bf) - a * mm;
  ab[ch] = a;
  ab[256 + ch] = b;
}

// ---- fused A-fragment load: norm(cpart) + skip(lp) + ELU, f2b to bf16 --------------
__device__ __forceinline__ void load_af_fused(short8* af, const u16* cpb, const u16* lpb,
                                              const float* __restrict__ ab, int q) {
  #pragma unroll
  for (int i = 0; i < 8; ++i) {
    int ch0 = q * 8 + i * 32;
    u16x4 c0 = *(const u16x4*)(cpb + i * 32);
    u16x4 c1 = *(const u16x4*)(cpb + i * 32 + 4);
    u16x4 l0 = *(const u16x4*)(lpb + i * 32);
    u16x4 l1 = *(const u16x4*)(lpb + i * 32 + 4);
    f32x4 a0 = *(const f32x4*)(ab + ch0);
    f32x4 a1 = *(const f32x4*)(ab + ch0 + 4);
    f32x4 b0 = *(const f32x4*)(ab + 256 + ch0);
    f32x4 b1 = *(const f32x4*)(ab + 256 + ch0 + 4);
    short8 w;
    #pragma unroll
    for (int j = 0; j < 4; ++j) {
      float y = a0[j] * b2f(c0[j]) + b0[j] + b2f(l0[j]);
      y = y > 0.f ? y : expm1f(y);
      w[j] = (short)f2b(y);
      float y2 = a1[j] * b2f(c1[j]) + b1[j] + b2f(l1[j]);
      y2 = y2 > 0.f ? y2 : expm1f(y2);
      w[j + 4] = (short)f2b(y2);
    }
    af[i] = w;
  }
}

// ------- fused GEMM: (M x 256) x (256 x 768), A-resident + LDS-staged B -------------
// Operand-SWAPPED MFMA (D = W^T * X^T): each lane owns one node row, 4 consecutive
// channels per acc -> u16x4 stores. fuse=1: A comes from norm(cpart)+lp+ELU inline.
__global__ __launch_bounds__(256) void gemm_kernel(
    const u16* __restrict__ A, const u16* __restrict__ wpack, const void* blin,
    const int* flags, int layer,
    u16* __restrict__ xl, u16* __restrict__ xr, u16* __restrict__ lp, int M,
    const u16* __restrict__ cp, const u16* __restrict__ lpin,
    const float* __restrict__ ab, int fuse) {
  __shared__ __align__(16) u16 bsh[16384];   // 32 KB: [kk 0..31][col 0..63][j 0..7]
  int wave = threadIdx.x >> 6;
  int lane = threadIdx.x & 63;
  int q = lane >> 4;
  int t = lane & 15;
  int m0 = blockIdx.x * 64 + wave * 16;
  int yh = blockIdx.y;

  int arow = m0 + t;
  if (arow >= M) arow = M - 1;
  short8 af[8];
  if (fuse) {
    const u16* cpb = cp + (size_t)arow * DD + q * 8;
    const u16* lpb = lpin + (size_t)arow * DD + q * 8;
    load_af_fused(af, cpb, lpb, ab, q);
  } else {
    const u16* Abase = A + (size_t)arow * DD + q * 8;
    #pragma unroll
    for (int i = 0; i < 8; ++i) af[i] = *(const short8*)(Abase + i * 32);
  }

  int bf = flags[0];
  int m = m0 + t;                 // output row owned by this lane (swapped layout)

  for (int yi = 0; yi < 6; ++yi) {
    int y = yh * 6 + yi;
    int mm = y >> 2;
    int col0 = (y & 3) * 64;
    const u16* wb = wpack + (mm << 16);

    __syncthreads();   // previous iteration's LDS reads complete
    #pragma unroll
    for (int itc = 0; itc < 8; ++itc) {
      int kk = wave + itc * 4;                       // = chunk>>6, uniform per wave
      const u16* gp = wb + (((kk << 8) + col0) << 3) + (lane << 3);
      u16* lb = &bsh[(wave * 64 + itc * 256) << 3];  // wave-uniform base
      gload_lds16(gp, lb);
    }
    __syncthreads();   // drains vmcnt (global_load_lds) before LDS reads

    f32x4 acc[4];
    #pragma unroll
    for (int ns = 0; ns < 4; ++ns) acc[ns] = (f32x4){0.f, 0.f, 0.f, 0.f};

    #pragma unroll
    for (int i = 0; i < 8; ++i) {
      int kk = i * 4 + q;
      const u16* bb = &bsh[(kk << 9) + (t << 3)];
      #pragma unroll
      for (int ns = 0; ns < 4; ++ns) {
        short8 b = *(const short8*)(bb + (ns << 7));
        // swapped: weights as A-operand, x-rows as B-operand
        acc[ns] = __builtin_amdgcn_mfma_f32_16x16x32_bf16(b, af[i], acc[ns], 0, 0, 0);
      }
    }

    u16* dstp = (y < 4) ? xl : (y < 8) ? xr : lp;
    bool isLp = (y >= 8);
    if (m < M) {
      #pragma unroll
      for (int ns = 0; ns < 4; ++ns) {
        int c0 = col0 + ns * 16 + q * 4;
        u16x4 w;
        #pragma unroll
        for (int r = 0; r < 4; ++r) {
          float bias = isLp ? ldf(blin, layer * 256 + c0 + r, bf) : 0.f;
          w[r] = f2b(acc[ns][r] + bias);
        }
        *(u16x4*)(dstp + (size_t)m * DD + c0) = w;
      }
    }
  }
}

// ------ final GEMM via MFMA: norm-fused emb @ [fWl|fWr|fWlin] -> zl/zr [N][32], lp [N][8]
__global__ __launch_bounds__(256) void fgemm_kernel(
    const u16* __restrict__ cp, const u16* __restrict__ lpin,
    const float* __restrict__ ab, const u16* __restrict__ fwp, const void* fblin,
    const int* flags, float* __restrict__ zl, float* __restrict__ zr,
    float* __restrict__ lp5, int M) {
  int wave = threadIdx.x >> 6;
  int lane = threadIdx.x & 63;
  int q = lane >> 4;
  int t = lane & 15;
  int m0 = blockIdx.x * 64 + wave * 16;

  f32x4 acc[3];
  #pragma unroll
  for (int ns = 0; ns < 3; ++ns) acc[ns] = (f32x4){0.f, 0.f, 0.f, 0.f};

  int arow = m0 + t;
  if (arow >= M) arow = M - 1;
  short8 af[8];
  {
    const u16* cpb = cp + (size_t)arow * DD + q * 8;
    const u16* lpb = lpin + (size_t)arow * DD + q * 8;
    load_af_fused(af, cpb, lpb, ab, q);
  }

  #pragma unroll
  for (int k0 = 0; k0 < DD; k0 += 32) {
    short8 a = af[k0 >> 5];
    int kk = (k0 >> 3) + q;
    #pragma unroll
    for (int ns = 0; ns < 3; ++ns) {
      short8 b = *(const short8*)(fwp + (((kk * 48) + ns * 16 + t) << 3));
      acc[ns] = __builtin_amdgcn_mfma_f32_16x16x32_bf16(a, b, acc[ns], 0, 0, 0);
    }
  }

  int bf = flags[0];
  #pragma unroll
  for (int ns = 0; ns < 3; ++ns) {
    int c = ns * 16 + t;
    #pragma unroll
    for (int r = 0; r < 4; ++r) {
      int row = m0 + q * 4 + r;
      if (row < M) {
        float v = acc[ns][r];
        if (c < 20) {
          zl[row * 32 + (c / 5) * 8 + (c % 5)] = v;
        } else if (c < 40) {
          int c2 = c - 20;
          zr[row * 32 + (c2 / 5) * 8 + (c2 % 5)] = v;
        } else if (c < 45) {
          lp5[row * 8 + (c - 40)] = v + ldf(fblin, c - 40, bf);
        }
      }
    }
  }
}

// ------- GATv2 aggregation: 4 nodes/block (wave=node), scalar math + DPP reduce -----
__device__ __forceinline__ void edge_step(u16x4 s4, const float* xrv, const float* atv,
                                          float& l, float* acc) {
  float x0 = b2f(s4[0]), x1 = b2f(s4[1]), x2 = b2f(s4[2]), x3 = b2f(s4[3]);
  float sp = atv[0] * lrelu(x0 + xrv[0]) + atv[1] * lrelu(x1 + xrv[1]) +
             atv[2] * lrelu(x2 + xrv[2]) + atv[3] * lrelu(x3 + xrv[3]);
  sp = row16_allsum(sp);        // bit-identical to shfl_xor{1,2,4,8}, zero DS ops
  float pz = cexp(sp);
  l += pz;
  acc[0] += pz * x0;
  acc[1] += pz * x1;
  acc[2] += pz * x2;
  acc[3] += pz * x3;
}

__global__ __launch_bounds__(256) void agg_kernel(
    const u16* __restrict__ xl, const u16* __restrict__ xr,
    const int* __restrict__ rowptr, const int* __restrict__ col,
    const void* att, const void* bconv, const int* flags, int layer,
    u16* __restrict__ cpart) {
  int wave = threadIdx.x >> 6;
  int node = blockIdx.x * 4 + wave;   // NN % 4 == 0, grid = NN/4
  int lane = threadIdx.x & 63;
  int h = lane >> 4;
  int cb = (lane & 15) * 4;
  int base = h * 64 + cb;
  int bf = flags[0];

  u16x4 r4 = *(const u16x4*)(xr + (size_t)node * DD + base);
  float xrv[4], atv[4];
  #pragma unroll
  for (int j = 0; j < 4; ++j) {
    xrv[j] = b2f(r4[j]);
    atv[j] = ldf(att, layer * 256 + base + j, bf);
  }

  float l = 0.f;
  float acc[4] = {0.f, 0.f, 0.f, 0.f};
  int e0 = rowptr[node], e1 = rowptr[node + 1];
  const char* xlb = (const char*)xl;          // SGPR base; 32-bit voffset per gather
  u32 baseb = (u32)(base << 1);

  int e = e0;
  for (; e < e1 && (e & 3); ++e) {            // align to 16B for int4 col loads
    u16x4 v = *(const u16x4*)(xlb + (((u32)col[e] << 9) + baseb));
    edge_step(v, xrv, atv, l, acc);
  }
  int nq = (e1 - e) >> 2;
  if (nq > 0) {
    i32x4 cq = *(const i32x4*)(col + e);      // software-pipelined col prefetch
    for (int g = 0; g < nq; ++g) {
      i32x4 nx = (g + 1 < nq) ? *(const i32x4*)(col + e + 4) : cq;
      u16x4 v0 = *(const u16x4*)(xlb + (((u32)cq.x << 9) + baseb));
      u16x4 v1 = *(const u16x4*)(xlb + (((u32)cq.y << 9) + baseb));
      u16x4 v2 = *(const u16x4*)(xlb + (((u32)cq.z << 9) + baseb));
      u16x4 v3 = *(const u16x4*)(xlb + (((u32)cq.w << 9) + baseb));
      edge_step(v0, xrv, atv, l, acc);
      edge_step(v1, xrv, atv, l, acc);
      edge_step(v2, xrv, atv, l, acc);
      edge_step(v3, xrv, atv, l, acc);
      cq = nx;
      e += 4;
    }
  }
  for (; e < e1; ++e) {
    u16x4 v = *(const u16x4*)(xlb + (((u32)col[e] << 9) + baseb));
    edge_step(v, xrv, atv, l, acc);
  }

  float inv = 1.f / (l + 1e-16f);
  u16x4 outw;
  #pragma unroll
  for (int j = 0; j < 4; ++j)
    outw[j] = f2b(acc[j] * inv + ldf(bconv, layer * 256 + base + j, bf));
  *(u16x4*)(cpart + (size_t)node * DD + base) = outw;
}

// ---------------- GraphNorm stats (bf16 input); sums is layer-specific ptr ----------
__global__ __launch_bounds__(256) void stats_kernel(const u16* __restrict__ cpart,
                                                    float* __restrict__ sums) {
  int ch = threadIdx.x;
  int n0 = blockIdx.x * 100, n1 = n0 + 100;
  float s = 0.f, s2 = 0.f;
  for (int n = n0; n < n1; ++n) {
    float x = b2f(cpart[(size_t)n * DD + ch]);
    s += x; s2 += x * x;
  }
  atomicAdd(&sums[ch], s);
  atomicAdd(&sums[256 + ch], s2);
}

// ------------ final aggregation: 4 nodes/block, 16 edge-lanes/head, f32x4 zl --------
__global__ __launch_bounds__(256) void finagg_kernel(
    const float* __restrict__ zl, const float* __restrict__ zr,
    const int* __restrict__ rowptr, const int* __restrict__ col,
    const void* fatt, const void* fbconv, const int* flags,
    const float* __restrict__ lp5, void* outv) {
  int node = blockIdx.x * 4 + (threadIdx.x >> 6);   // NN % 4 == 0, grid = NN/4
  int lane = threadIdx.x & 63;
  int bf = flags[0];
  int h = lane >> 4, sub = lane & 15;

  const float* zrp = zr + node * 32 + h * 8;        // 16B-aligned by layout
  f32x4 zr4 = *(const f32x4*)zrp;
  float zrv[5] = {zr4.x, zr4.y, zr4.z, zr4.w, zrp[4]};
  float atv[5];
  #pragma unroll
  for (int c = 0; c < 5; ++c) atv[c] = ldf(fatt, h * 5 + c, bf);

  float l = 0.f, acc[5] = {0.f, 0.f, 0.f, 0.f, 0.f};
  int e0 = rowptr[node], e1 = rowptr[node + 1];
  for (int e = e0 + sub; e < e1; e += 16) {
    int src = col[e];
    const float* zs = zl + src * 32 + h * 8;        // 16B-aligned
    f32x4 z4 = *(const f32x4*)zs;
    float z4s = zs[4];
    float zlv[5] = {z4.x, z4.y, z4.z, z4.w, z4s};
    float s = 0.f;
    #pragma unroll
    for (int c = 0; c < 5; ++c) s += atv[c] * lrelu(zlv[c] + zrv[c]);
    float pz = cexp(s);
    l += pz;
    #pragma unroll
    for (int c = 0; c < 5; ++c) acc[c] += pz * zlv[c];
  }
  #pragma unroll
  for (int off = 1; off < 16; off <<= 1) {
    l += __shfl_xor(l, off);
    #pragma unroll
    for (int c = 0; c < 5; ++c) acc[c] += __shfl_xor(acc[c], off);
  }
  float inv = 1.f / (l + 1e-16f);
  float v[5];
  #pragma unroll
  for (int c = 0; c < 5; ++c) {
    float tv = acc[c] * inv;
    tv += __shfl_xor(tv, 16);
    tv += __shfl_xor(tv, 32);
    v[c] = tv * 0.25f;
  }
  if (lane == 0) {
    float mx = -3.0e38f;
    #pragma unroll
    for (int c = 0; c < 5; ++c) {
      v[c] += ldf(fbconv, c, bf) + lp5[node * 8 + c];
      mx = fmaxf(mx, v[c]);
    }
    float se = 0.f;
    #pragma unroll
    for (int c = 0; c < 5; ++c) se += __expf(v[c] - mx);
    float lse = mx + __logf(se);
    #pragma unroll
    for (int c = 0; c < 5; ++c) {
      float r = v[c] - lse;
      if (bf) ((u16*)outv)[node * 5 + c] = f2b(r);
      else    ((float*)outv)[node * 5 + c] = r;
    }
  }
}

extern "C" void kernel_launch(void* const* d_in, const int* in_sizes, int n_in,
                              void* d_out, int out_size, void* d_ws, size_t ws_size,
                              hipStream_t stream) {
  (void)in_sizes; (void)n_in; (void)out_size; (void)ws_size;
  const void* x     = d_in[0];
  const void* ei    = d_in[1];
  const void* Wl    = d_in[2];
  const void* Wr    = d_in[3];
  const void* att   = d_in[4];
  const void* bconv = d_in[5];
  const void* Wlin  = d_in[6];
  const void* blin  = d_in[7];
  const void* gnw   = d_in[8];
  const void* gnb   = d_in[9];
  const void* gnms  = d_in[10];
  const void* fWl   = d_in[11];
  const void* fWr   = d_in[12];
  const void* fatt  = d_in[13];
  const void* fbc   = d_in[14];
  const void* fWlin = d_in[15];
  const void* fblin = d_in[16];

  char* p = (char*)d_ws;
  auto take = [&](size_t bytes) {
    char* r = p;
    p += (bytes + 511) & ~(size_t)511;
    return r;
  };
  int* flags   = (int*)take(512);
  int* rowptr  = (int*)take((NN + 1) * sizeof(int));
  int* cnt     = (int*)take(NN * sizeof(int));
  int* colx    = (int*)take(EE * sizeof(int));
  int* bsum    = (int*)take(256 * sizeof(int));
  int* boff    = (int*)take(256 * sizeof(int));
  u16* wpack   = (u16*)take((size_t)6 * 65536 * sizeof(u16));
  u16* fwp     = (u16*)take((size_t)32 * 48 * 8 * sizeof(u16));
  float* sums  = (float*)take(1024 * sizeof(float));   // [layer][s|s2][256]
  float* ab    = (float*)take(1024 * sizeof(float));   // [layer][a|b][256]
  // unionA: xb (layer-0 GEMM input) -> cpart bf16 (agg out, read by fused consumers).
  char* unionA = take((size_t)NN * DD * 4);
  u16* xb      = (u16*)unionA;
  u16* cpart   = (u16*)unionA;
  u16* xl      = (u16*)take((size_t)NN * DD * 2);
  u16* xr      = (u16*)take((size_t)NN * DD * 2);
  u16* lpA     = (u16*)take((size_t)NN * DD * 2);
  u16* lpB     = (u16*)take((size_t)NN * DD * 2);
  // final-stage reuse (free by then): zl->xl, zr->xr, lp5->lpA
  float* zl    = (float*)xl;
  float* zr    = (float*)xr;
  float* lp5   = (float*)lpA;

  init_kernel<<<dim3(NB), dim3(256), 0, stream>>>(x, ei, flags, cnt, sums);
  hist_kernel<<<dim3((EE + 255) / 256), dim3(256), 0, stream>>>(ei, flags, cnt);
  bsum_kernel<<<dim3(NB), dim3(256), 0, stream>>>(cnt, bsum);
  bscan_kernel<<<dim3(1), dim3(256), 0, stream>>>(bsum, boff);
  bwrite_kernel<<<dim3(NB), dim3(256), 0, stream>>>(cnt, boff, rowptr);
  fill_kernel<<<dim3((EE + 255) / 256), dim3(256), 0, stream>>>(ei, flags, rowptr, cnt, colx);
  prep_kernel<<<dim3(1584 + NN * DD / 1024), dim3(256), 0, stream>>>(
      Wl, Wr, Wlin, fWl, fWr, fWlin, x, flags, wpack, fwp, xb);

  // ---- layer 0: raw A from xb ----
  gemm_kernel<<<dim3((NN + 63) / 64, 2), dim3(256), 0, stream>>>(
      xb, wpack, blin, flags, 0, xl, xr, lpA, NN, xb, xb, ab, 0);
  agg_kernel<<<dim3(NN / 4), dim3(256), 0, stream>>>(xl, xr, rowptr, colx, att, bconv,
                                                     flags, 0, cpart);
  stats_kernel<<<dim3(500), dim3(256), 0, stream>>>(cpart, sums);
  nprep_kernel<<<dim3(1), dim3(256), 0, stream>>>(sums, gnw, gnb, gnms, flags, 0, ab);

  // ---- layer 1: A = elu(norm(cpart) + lpA) fused into A-load ----
  gemm_kernel<<<dim3((NN + 63) / 64, 2), dim3(256), 0, stream>>>(
      xb, wpack + (size_t)3 * 65536, blin, flags, 1, xl, xr, lpB, NN, cpart, lpA, ab, 1);
  agg_kernel<<<dim3(NN / 4), dim3(256), 0, stream>>>(xl, xr, rowptr, colx, att, bconv,
                                                     flags, 1, cpart);
  stats_kernel<<<dim3(500), dim3(256), 0, stream>>>(cpart, sums + 512);
  nprep_kernel<<<dim3(1), dim3(256), 0, stream>>>(sums, gnw, gnb, gnms, flags, 1, ab + 512);

  // ---- final: A = elu(norm(cpart) + lpB) fused ----
  fgemm_kernel<<<dim3((NN + 63) / 64), dim3(256), 0, stream>>>(
      cpart, lpB, ab + 512, fwp, fblin, flags, zl, zr, lp5, NN);
  finagg_kernel<<<dim3(NN / 4), dim3(256), 0, stream>>>(zl, zr, rowptr, colx, fatt, fbc,
                                                        flags, lp5, d_out);
}

// Round 6
// 531.993 us; speedup vs baseline: 1.3014x; 1.0289x over previous
//
#include <hip/hip_runtime.h>

#define NN 50000
#define EE 800000
#define DD 256
#define NB 196   // ceil(NN/256)

typedef unsigned short u16;
typedef unsigned int u32;

typedef __attribute__((ext_vector_type(8))) short short8;
typedef __attribute__((ext_vector_type(4))) float f32x4;
typedef __attribute__((ext_vector_type(4))) unsigned short u16x4;
typedef __attribute__((ext_vector_type(4))) int i32x4;

__device__ __forceinline__ float b2f(u16 u) {
  union { u32 i; float f; } c; c.i = ((u32)u) << 16; return c.f;
}
__device__ __forceinline__ u16 f2b(float f) {
  union { float f; u32 i; } c; c.f = f;
  u32 u = c.i;
  return (u16)((u + 0x7fffu + ((u >> 16) & 1u)) >> 16);
}
// slope<1: lrelu(x) == max(x, 0.2x) exactly
__device__ __forceinline__ float lrelu(float x) { return fmaxf(x, 0.2f * x); }
__device__ __forceinline__ float ldf(const void* p, int i, int bf) {
  return bf ? b2f(((const u16*)p)[i]) : ((const float*)p)[i];
}
__device__ __forceinline__ int lde(const void* ei, int idx, int m64) {
  int v = m64 ? (int)((const long long*)ei)[idx] : ((const int*)ei)[idx];
  return v < 0 ? 0 : (v >= NN ? NN - 1 : v);
}
// softmax without online max: shift-invariant, scores bounded -> exact vs ref
__device__ __forceinline__ float cexp(float s) {
  return __expf(__builtin_amdgcn_fmed3f(s, -60.f, 60.f));
}

// ---- DPP 16-lane butterfly add: bit-identical to shfl_xor{1,2,4,8} chain ----
template <int CTRL>
__device__ __forceinline__ float dpp_add(float s) {
  union { float f; int i; } a, b;
  a.f = s;
  b.i = __builtin_amdgcn_update_dpp(0, a.i, CTRL, 0xf, 0xf, true);
  return s + b.f;
}
__device__ __forceinline__ float row16_allsum(float s) {
  s = dpp_add<0xB1>(s);
  s = dpp_add<0x4E>(s);
  s = dpp_add<0x141>(s);
  s = dpp_add<0x140>(s);
  return s;
}

// ---- async global->LDS (16B/lane, dest = wave-uniform base + lane*16) ----
__device__ __forceinline__ void gload_lds16(const void* g, void* l) {
  __builtin_amdgcn_global_load_lds(
      (const __attribute__((address_space(1))) void*)g,
      (__attribute__((address_space(3))) void*)l, 16, 0, 0);
}

// ------- init: zero cnt + zero sums (both layers) + dtype detection ----------------
__global__ __launch_bounds__(256) void init_kernel(const void* x, const void* ei,
                                                   int* flags, int* cnt,
                                                   float* sums) {
  int i = blockIdx.x * 256 + threadIdx.x;
  if (i < NN) cnt[i] = 0;
  if (blockIdx.x == 1) {
    #pragma unroll
    for (int j = 0; j < 4; ++j) sums[threadIdx.x + j * 256] = 0.f;
  }
  if (blockIdx.x == 0 && threadIdx.x < 64) {
    int lane = threadIdx.x;
    const u16* xw = (const u16*)x;
    int c = 0;
    for (int k = lane; k < 512; k += 64) {
      u16 w = xw[k];
      int e = (w >> 7) & 0xFF;
      if ((e >= 107 && e <= 147) || (w & 0x7FFF) == 0) ++c;
    }
    const u32* ew = (const u32*)ei;
    int zc = 0;
    for (int k = 1 + 2 * lane; k < 1024; k += 128)
      if (ew[k] == 0) ++zc;
    #pragma unroll
    for (int off = 1; off < 64; off <<= 1) {
      c += __shfl_xor(c, off);
      zc += __shfl_xor(zc, off);
    }
    if (lane == 0) {
      flags[0] = (c >= 440) ? 1 : 0;
      flags[1] = (zc >= 400) ? 1 : 0;
    }
  }
}

// ---------------- CSR build ----------------
__global__ void hist_kernel(const void* ei, const int* flags, int* cnt) {
  int e = blockIdx.x * 256 + threadIdx.x;
  if (e < EE) atomicAdd(&cnt[lde(ei, EE + e, flags[1])], 1);
}

// -------- parallel 3-phase exclusive scan of deg[NN] -> rowptr[NN+1] --------
__global__ __launch_bounds__(256) void bsum_kernel(const int* __restrict__ deg,
                                                   int* __restrict__ bsum) {
  int i = blockIdx.x * 256 + threadIdx.x;
  int v = (i < NN) ? deg[i] : 0;
  #pragma unroll
  for (int off = 1; off < 64; off <<= 1) v += __shfl_xor(v, off);
  __shared__ int ws[4];
  int lane = threadIdx.x & 63, wid = threadIdx.x >> 6;
  if (lane == 0) ws[wid] = v;
  __syncthreads();
  if (threadIdx.x == 0) bsum[blockIdx.x] = ws[0] + ws[1] + ws[2] + ws[3];
}

__global__ __launch_bounds__(256) void bscan_kernel(const int* __restrict__ bsum,
                                                    int* __restrict__ boff) {
  int t = threadIdx.x;
  int v = (t < NB) ? bsum[t] : 0;
  int iv = v;
  int lane = t & 63, wid = t >> 6;
  #pragma unroll
  for (int off = 1; off < 64; off <<= 1) {
    int u = __shfl_up(iv, off);
    if (lane >= off) iv += u;
  }
  __shared__ int ws[4];
  if (lane == 63) ws[wid] = iv;
  __syncthreads();
  int add = 0;
  for (int w = 0; w < wid; ++w) add += ws[w];
  if (t < NB) boff[t] = iv - v + add;
}

__global__ __launch_bounds__(256) void bwrite_kernel(const int* __restrict__ deg,
                                                     const int* __restrict__ boff,
                                                     int* __restrict__ rowptr) {
  int i = blockIdx.x * 256 + threadIdx.x;
  int v = (i < NN) ? deg[i] : 0;
  int iv = v;
  int lane = threadIdx.x & 63, wid = threadIdx.x >> 6;
  #pragma unroll
  for (int off = 1; off < 64; off <<= 1) {
    int u = __shfl_up(iv, off);
    if (lane >= off) iv += u;
  }
  __shared__ int ws[4];
  if (lane == 63) ws[wid] = iv;
  __syncthreads();
  int add = boff[blockIdx.x];
  for (int w = 0; w < wid; ++w) add += ws[w];
  if (i <= NN) rowptr[i] = iv - v + add;
}

// uses hist counts (cnt[dst]=deg) via atomicSub -> no second memset needed
__global__ void fill_kernel(const void* ei, const int* flags, const int* __restrict__ rowptr,
                            int* __restrict__ cnt, int* __restrict__ col) {
  int e = blockIdx.x * 256 + threadIdx.x;
  if (e < EE) {
    int m64 = flags[1];
    int dst = lde(ei, EE + e, m64);
    int old = atomicSub(&cnt[dst], 1);
    int pos = rowptr[dst] + old - 1;
    if (pos >= 0 && pos < EE) col[pos] = lde(ei, e, m64);
  }
}

// -------- prep: weight pack (MFMA B-frag order) + final-weight pack ------------------
// grid 1584: [0,1536) pack wpack, [1536,1584) pack fwp. (x-conversion fused into gemm.)
__global__ __launch_bounds__(256) void prep_kernel(
    const void* Wl, const void* Wr, const void* Wlin,
    const void* fWl, const void* fWr, const void* fWlin,
    const int* flags, u16* wpack, u16* fwp) {
  int bf = flags[0];
  int bid = blockIdx.x;
  if (bid < 1536) {
    int idx = bid * 256 + threadIdx.x;
    int m = idx >> 16, e = idx & 65535;
    int layer = (m >= 3) ? 1 : 0, sel = m - layer * 3;
    const void* src = (sel == 0 ? Wl : (sel == 1 ? Wr : Wlin));
    int k = e >> 8, n = e & 255;
    wpack[(m << 16) + ((((k >> 3) << 8) + n) << 3) + (k & 7)] =
        f2b(ldf(src, layer * 65536 + e, bf));
  } else {
    int idx = (bid - 1536) * 256 + threadIdx.x;
    int j = idx & 7;
    int col = (idx >> 3) % 48;
    int kk = idx / (48 * 8);
    int k = kk * 8 + j;
    float v = 0.f;
    if (col < 20)      v = ldf(fWl, k * 20 + col, bf);
    else if (col < 40) v = ldf(fWr, k * 20 + (col - 20), bf);
    else if (col < 45) v = ldf(fWlin, k * 5 + (col - 40), bf);
    fwp[idx] = f2b(v);
  }
}

// ------ nprep: GraphNorm stats -> per-channel affine (a,b): y = a*x + b + lp --------
__global__ __launch_bounds__(256) void nprep_kernel(
    const float* __restrict__ sums, const void* gw, const void* gb, const void* gms,
    const int* flags, int layer, float* __restrict__ ab) {
  int ch = threadIdx.x;
  int bf = flags[0];
  const float invN = 1.f / (float)NN;
  float mean = sums[layer * 512 + ch] * invN;
  float ex2 = sums[layer * 512 + 256 + ch] * invN;
  float mm = mean * ldf(gms, layer * 256 + ch, bf);
  float var = ex2 - 2.f * mm * mean + mm * mm;
  float rs = rsqrtf(fmaxf(var, 0.f) + 1e-5f);
  float a = ldf(gw, layer * 256 + ch, bf) * rs;
  float b = ldf(gb, layer * 256 + ch, bf) - a * mm;
  ab[ch] = a;
  ab[256 + ch] = b;
}

// ---- fused A-fragment load: norm(cpart) + skip(lp) + ELU, f2b to bf16 --------------
__device__ __forceinline__ void load_af_fused(short8* af, const u16* cpb, const u16* lpb,
                                              const float* __restrict__ ab, int q) {
  #pragma unroll
  for (int i = 0; i < 8; ++i) {
    int ch0 = q * 8 + i * 32;
    u16x4 c0 = *(const u16x4*)(cpb + i * 32);
    u16x4 c1 = *(const u16x4*)(cpb + i * 32 + 4);
    u16x4 l0 = *(const u16x4*)(lpb + i * 32);
    u16x4 l1 = *(const u16x4*)(lpb + i * 32 + 4);
    f32x4 a0 = *(const f32x4*)(ab + ch0);
    f32x4 a1 = *(const f32x4*)(ab + ch0 + 4);
    f32x4 b0 = *(const f32x4*)(ab + 256 + ch0);
    f32x4 b1 = *(const f32x4*)(ab + 256 + ch0 + 4);
    short8 w;
    #pragma unroll
    for (int j = 0; j < 4; ++j) {
      float y = a0[j] * b2f(c0[j]) + b0[j] + b2f(l0[j]);
      y = y > 0.f ? y : expm1f(y);
      w[j] = (short)f2b(y);
      float y2 = a1[j] * b2f(c1[j]) + b1[j] + b2f(l1[j]);
      y2 = y2 > 0.f ? y2 : expm1f(y2);
      w[j + 4] = (short)f2b(y2);
    }
    af[i] = w;
  }
}

// ------- fused GEMM: (M x 256) x (256 x 768), A-resident + LDS-staged B -------------
// Operand-SWAPPED MFMA (D = W^T * X^T); full y=0..11 loop per block so the A panel
// (and its fused norm/convert work) is loaded exactly ONCE per row.
// fuse=1: A = elu(norm(cpart)+lp) inline. fuse=2: A = raw x (bf16 or f32->bf16).
__global__ __launch_bounds__(256) void gemm_kernel(
    const void* __restrict__ xsrc, const u16* __restrict__ wpack, const void* blin,
    const int* flags, int layer,
    u16* __restrict__ xl, u16* __restrict__ xr, u16* __restrict__ lp, int M,
    const u16* __restrict__ cp, const u16* __restrict__ lpin,
    const float* __restrict__ ab, int fuse) {
  __shared__ __align__(16) u16 bsh[16384];   // 32 KB: [kk 0..31][col 0..63][j 0..7]
  int wave = threadIdx.x >> 6;
  int lane = threadIdx.x & 63;
  int q = lane >> 4;
  int t = lane & 15;
  int m0 = blockIdx.x * 64 + wave * 16;

  int arow = m0 + t;
  if (arow >= M) arow = M - 1;
  int bf = flags[0];
  short8 af[8];
  if (fuse == 1) {
    const u16* cpb = cp + (size_t)arow * DD + q * 8;
    const u16* lpb = lpin + (size_t)arow * DD + q * 8;
    load_af_fused(af, cpb, lpb, ab, q);
  } else {                       // fuse == 2: raw x, dtype-switched
    if (bf) {
      const u16* Abase = (const u16*)xsrc + (size_t)arow * DD + q * 8;
      #pragma unroll
      for (int i = 0; i < 8; ++i) af[i] = *(const short8*)(Abase + i * 32);
    } else {
      const float* Fb = (const float*)xsrc + (size_t)arow * DD + q * 8;
      #pragma unroll
      for (int i = 0; i < 8; ++i) {
        f32x4 s0 = *(const f32x4*)(Fb + i * 32);
        f32x4 s1 = *(const f32x4*)(Fb + i * 32 + 4);
        short8 w;
        #pragma unroll
        for (int j = 0; j < 4; ++j) {
          w[j] = (short)f2b(s0[j]);
          w[j + 4] = (short)f2b(s1[j]);
        }
        af[i] = w;
      }
    }
  }

  int m = m0 + t;                 // output row owned by this lane (swapped layout)

  for (int y = 0; y < 12; ++y) {
    int mm = y >> 2;
    int col0 = (y & 3) * 64;
    const u16* wb = wpack + (mm << 16);

    __syncthreads();   // previous iteration's LDS reads complete
    #pragma unroll
    for (int itc = 0; itc < 8; ++itc) {
      int kk = wave + itc * 4;                       // = chunk>>6, uniform per wave
      const u16* gp = wb + (((kk << 8) + col0) << 3) + (lane << 3);
      u16* lb = &bsh[(wave * 64 + itc * 256) << 3];  // wave-uniform base
      gload_lds16(gp, lb);
    }
    __syncthreads();   // drains vmcnt (global_load_lds) before LDS reads

    f32x4 acc[4];
    #pragma unroll
    for (int ns = 0; ns < 4; ++ns) acc[ns] = (f32x4){0.f, 0.f, 0.f, 0.f};

    #pragma unroll
    for (int i = 0; i < 8; ++i) {
      int kk = i * 4 + q;
      const u16* bb = &bsh[(kk << 9) + (t << 3)];
      #pragma unroll
      for (int ns = 0; ns < 4; ++ns) {
        short8 b = *(const short8*)(bb + (ns << 7));
        // swapped: weights as A-operand, x-rows as B-operand
        acc[ns] = __builtin_amdgcn_mfma_f32_16x16x32_bf16(b, af[i], acc[ns], 0, 0, 0);
      }
    }

    u16* dstp = (y < 4) ? xl : (y < 8) ? xr : lp;
    bool isLp = (y >= 8);
    if (m < M) {
      #pragma unroll
      for (int ns = 0; ns < 4; ++ns) {
        int c0 = col0 + ns * 16 + q * 4;
        u16x4 w;
        #pragma unroll
        for (int r = 0; r < 4; ++r) {
          float bias = isLp ? ldf(blin, layer * 256 + c0 + r, bf) : 0.f;
          w[r] = f2b(acc[ns][r] + bias);
        }
        *(u16x4*)(dstp + (size_t)m * DD + c0) = w;
      }
    }
  }
}

// ------ final GEMM via MFMA: norm-fused emb @ [fWl|fWr|fWlin] -> zl/zr [N][32], lp [N][8]
__global__ __launch_bounds__(256) void fgemm_kernel(
    const u16* __restrict__ cp, const u16* __restrict__ lpin,
    const float* __restrict__ ab, const u16* __restrict__ fwp, const void* fblin,
    const int* flags, float* __restrict__ zl, float* __restrict__ zr,
    float* __restrict__ lp5, int M) {
  int wave = threadIdx.x >> 6;
  int lane = threadIdx.x & 63;
  int q = lane >> 4;
  int t = lane & 15;
  int m0 = blockIdx.x * 64 + wave * 16;

  f32x4 acc[3];
  #pragma unroll
  for (int ns = 0; ns < 3; ++ns) acc[ns] = (f32x4){0.f, 0.f, 0.f, 0.f};

  int arow = m0 + t;
  if (arow >= M) arow = M - 1;
  short8 af[8];
  {
    const u16* cpb = cp + (size_t)arow * DD + q * 8;
    const u16* lpb = lpin + (size_t)arow * DD + q * 8;
    load_af_fused(af, cpb, lpb, ab, q);
  }

  #pragma unroll
  for (int k0 = 0; k0 < DD; k0 += 32) {
    short8 a = af[k0 >> 5];
    int kk = (k0 >> 3) + q;
    #pragma unroll
    for (int ns = 0; ns < 3; ++ns) {
      short8 b = *(const short8*)(fwp + (((kk * 48) + ns * 16 + t) << 3));
      acc[ns] = __builtin_amdgcn_mfma_f32_16x16x32_bf16(a, b, acc[ns], 0, 0, 0);
    }
  }

  int bf = flags[0];
  #pragma unroll
  for (int ns = 0; ns < 3; ++ns) {
    int c = ns * 16 + t;
    #pragma unroll
    for (int r = 0; r < 4; ++r) {
      int row = m0 + q * 4 + r;
      if (row < M) {
        float v = acc[ns][r];
        if (c < 20) {
          zl[row * 32 + (c / 5) * 8 + (c % 5)] = v;
        } else if (c < 40) {
          int c2 = c - 20;
          zr[row * 32 + (c2 / 5) * 8 + (c2 % 5)] = v;
        } else if (c < 45) {
          lp5[row * 8 + (c - 40)] = v + ldf(fblin, c - 40, bf);
        }
      }
    }
  }
}

// ------- GATv2 aggregation: 4 nodes/block (wave=node), scalar math + DPP reduce -----
__device__ __forceinline__ void edge_step(u16x4 s4, const float* xrv, const float* atv,
                                          float& l, float* acc) {
  float x0 = b2f(s4[0]), x1 = b2f(s4[1]), x2 = b2f(s4[2]), x3 = b2f(s4[3]);
  float sp = atv[0] * lrelu(x0 + xrv[0]) + atv[1] * lrelu(x1 + xrv[1]) +
             atv[2] * lrelu(x2 + xrv[2]) + atv[3] * lrelu(x3 + xrv[3]);
  sp = row16_allsum(sp);        // bit-identical to shfl_xor{1,2,4,8}, zero DS ops
  float pz = cexp(sp);
  l += pz;
  acc[0] += pz * x0;
  acc[1] += pz * x1;
  acc[2] += pz * x2;
  acc[3] += pz * x3;
}

__global__ __launch_bounds__(256) void agg_kernel(
    const u16* __restrict__ xl, const u16* __restrict__ xr,
    const int* __restrict__ rowptr, const int* __restrict__ col,
    const void* att, const void* bconv, const int* flags, int layer,
    u16* __restrict__ cpart) {
  int wave = threadIdx.x >> 6;
  int node = blockIdx.x * 4 + wave;   // NN % 4 == 0, grid = NN/4
  int lane = threadIdx.x & 63;
  int h = lane >> 4;
  int cb = (lane & 15) * 4;
  int base = h * 64 + cb;
  int bf = flags[0];

  u16x4 r4 = *(const u16x4*)(xr + (size_t)node * DD + base);
  float xrv[4], atv[4];
  #pragma unroll
  for (int j = 0; j < 4; ++j) {
    xrv[j] = b2f(r4[j]);
    atv[j] = ldf(att, layer * 256 + base + j, bf);
  }

  float l = 0.f;
  float acc[4] = {0.f, 0.f, 0.f, 0.f};
  int e0 = rowptr[node], e1 = rowptr[node + 1];
  const char* xlb = (const char*)xl;          // SGPR base; 32-bit voffset per gather
  u32 baseb = (u32)(base << 1);

  int e = e0;
  for (; e < e1 && (e & 3); ++e) {            // align to 16B for int4 col loads
    u16x4 v = *(const u16x4*)(xlb + (((u32)col[e] << 9) + baseb));
    edge_step(v, xrv, atv, l, acc);
  }
  int nq = (e1 - e) >> 2;
  if (nq > 0) {
    i32x4 cq = *(const i32x4*)(col + e);      // software-pipelined col prefetch
    for (int g = 0; g < nq; ++g) {
      i32x4 nx = (g + 1 < nq) ? *(const i32x4*)(col + e + 4) : cq;
      u16x4 v0 = *(const u16x4*)(xlb + (((u32)cq.x << 9) + baseb));
      u16x4 v1 = *(const u16x4*)(xlb + (((u32)cq.y << 9) + baseb));
      u16x4 v2 = *(const u16x4*)(xlb + (((u32)cq.z << 9) + baseb));
      u16x4 v3 = *(const u16x4*)(xlb + (((u32)cq.w << 9) + baseb));
      edge_step(v0, xrv, atv, l, acc);
      edge_step(v1, xrv, atv, l, acc);
      edge_step(v2, xrv, atv, l, acc);
      edge_step(v3, xrv, atv, l, acc);
      cq = nx;
      e += 4;
    }
  }
  for (; e < e1; ++e) {
    u16x4 v = *(const u16x4*)(xlb + (((u32)col[e] << 9) + baseb));
    edge_step(v, xrv, atv, l, acc);
  }

  float inv = 1.f / (l + 1e-16f);
  u16x4 outw;
  #pragma unroll
  for (int j = 0; j < 4; ++j)
    outw[j] = f2b(acc[j] * inv + ldf(bconv, layer * 256 + base + j, bf));
  *(u16x4*)(cpart + (size_t)node * DD + base) = outw;
}

// ---------------- GraphNorm stats (bf16 input); sums is layer-specific ptr ----------
__global__ __launch_bounds__(256) void stats_kernel(const u16* __restrict__ cpart,
                                                    float* __restrict__ sums) {
  int ch = threadIdx.x;
  int n0 = blockIdx.x * 100, n1 = n0 + 100;
  float s = 0.f, s2 = 0.f;
  for (int n = n0; n < n1; ++n) {
    float x = b2f(cpart[(size_t)n * DD + ch]);
    s += x; s2 += x * x;
  }
  atomicAdd(&sums[ch], s);
  atomicAdd(&sums[256 + ch], s2);
}

// ------------ final aggregation: 4 nodes/block, 16 edge-lanes/head, f32x4 zl --------
__global__ __launch_bounds__(256) void finagg_kernel(
    const float* __restrict__ zl, const float* __restrict__ zr,
    const int* __restrict__ rowptr, const int* __restrict__ col,
    const void* fatt, const void* fbconv, const int* flags,
    const float* __restrict__ lp5, void* outv) {
  int node = blockIdx.x * 4 + (threadIdx.x >> 6);   // NN % 4 == 0, grid = NN/4
  int lane = threadIdx.x & 63;
  int bf = flags[0];
  int h = lane >> 4, sub = lane & 15;

  const float* zrp = zr + node * 32 + h * 8;        // 16B-aligned by layout
  f32x4 zr4 = *(const f32x4*)zrp;
  float zrv[5] = {zr4.x, zr4.y, zr4.z, zr4.w, zrp[4]};
  float atv[5];
  #pragma unroll
  for (int c = 0; c < 5; ++c) atv[c] = ldf(fatt, h * 5 + c, bf);

  float l = 0.f, acc[5] = {0.f, 0.f, 0.f, 0.f, 0.f};
  int e0 = rowptr[node], e1 = rowptr[node + 1];
  for (int e = e0 + sub; e < e1; e += 16) {
    int src = col[e];
    const float* zs = zl + src * 32 + h * 8;        // 16B-aligned
    f32x4 z4 = *(const f32x4*)zs;
    float z4s = zs[4];
    float zlv[5] = {z4.x, z4.y, z4.z, z4.w, z4s};
    float s = 0.f;
    #pragma unroll
    for (int c = 0; c < 5; ++c) s += atv[c] * lrelu(zlv[c] + zrv[c]);
    float pz = cexp(s);
    l += pz;
    #pragma unroll
    for (int c = 0; c < 5; ++c) acc[c] += pz * zlv[c];
  }
  #pragma unroll
  for (int off = 1; off < 16; off <<= 1) {
    l += __shfl_xor(l, off);
    #pragma unroll
    for (int c = 0; c < 5; ++c) acc[c] += __shfl_xor(acc[c], off);
  }
  float inv = 1.f / (l + 1e-16f);
  float v[5];
  #pragma unroll
  for (int c = 0; c < 5; ++c) {
    float tv = acc[c] * inv;
    tv += __shfl_xor(tv, 16);
    tv += __shfl_xor(tv, 32);
    v[c] = tv * 0.25f;
  }
  if (lane == 0) {
    float mx = -3.0e38f;
    #pragma unroll
    for (int c = 0; c < 5; ++c) {
      v[c] += ldf(fbconv, c, bf) + lp5[node * 8 + c];
      mx = fmaxf(mx, v[c]);
    }
    float se = 0.f;
    #pragma unroll
    for (int c = 0; c < 5; ++c) se += __expf(v[c] - mx);
    float lse = mx + __logf(se);
    #pragma unroll
    for (int c = 0; c < 5; ++c) {
      float r = v[c] - lse;
      if (bf) ((u16*)outv)[node * 5 + c] = f2b(r);
      else    ((float*)outv)[node * 5 + c] = r;
    }
  }
}

extern "C" void kernel_launch(void* const* d_in, const int* in_sizes, int n_in,
                              void* d_out, int out_size, void* d_ws, size_t ws_size,
                              hipStream_t stream) {
  (void)in_sizes; (void)n_in; (void)out_size; (void)ws_size;
  const void* x     = d_in[0];
  const void* ei    = d_in[1];
  const void* Wl    = d_in[2];
  const void* Wr    = d_in[3];
  const void* att   = d_in[4];
  const void* bconv = d_in[5];
  const void* Wlin  = d_in[6];
  const void* blin  = d_in[7];
  const void* gnw   = d_in[8];
  const void* gnb   = d_in[9];
  const void* gnms  = d_in[10];
  const void* fWl   = d_in[11];
  const void* fWr   = d_in[12];
  const void* fatt  = d_in[13];
  const void* fbc   = d_in[14];
  const void* fWlin = d_in[15];
  const void* fblin = d_in[16];

  char* p = (char*)d_ws;
  auto take = [&](size_t bytes) {
    char* r = p;
    p += (bytes + 511) & ~(size_t)511;
    return r;
  };
  int* flags   = (int*)take(512);
  int* rowptr  = (int*)take((NN + 1) * sizeof(int));
  int* cnt     = (int*)take(NN * sizeof(int));
  int* colx    = (int*)take(EE * sizeof(int));
  int* bsum    = (int*)take(256 * sizeof(int));
  int* boff    = (int*)take(256 * sizeof(int));
  u16* wpack   = (u16*)take((size_t)6 * 65536 * sizeof(u16));
  u16* fwp     = (u16*)take((size_t)32 * 48 * 8 * sizeof(u16));
  float* sums  = (float*)take(1024 * sizeof(float));   // [layer][s|s2][256]
  float* ab    = (float*)take(1024 * sizeof(float));   // [layer][a|b][256]
  u16* cpart   = (u16*)take((size_t)NN * DD * 2);
  u16* xl      = (u16*)take((size_t)NN * DD * 2);
  u16* xr      = (u16*)take((size_t)NN * DD * 2);
  u16* lpA     = (u16*)take((size_t)NN * DD * 2);
  u16* lpB     = (u16*)take((size_t)NN * DD * 2);
  // final-stage reuse (free by then): zl->xl, zr->xr, lp5->lpA
  float* zl    = (float*)xl;
  float* zr    = (float*)xr;
  float* lp5   = (float*)lpA;

  init_kernel<<<dim3(NB), dim3(256), 0, stream>>>(x, ei, flags, cnt, sums);
  hist_kernel<<<dim3((EE + 255) / 256), dim3(256), 0, stream>>>(ei, flags, cnt);
  bsum_kernel<<<dim3(NB), dim3(256), 0, stream>>>(cnt, bsum);
  bscan_kernel<<<dim3(1), dim3(256), 0, stream>>>(bsum, boff);
  bwrite_kernel<<<dim3(NB), dim3(256), 0, stream>>>(cnt, boff, rowptr);
  fill_kernel<<<dim3((EE + 255) / 256), dim3(256), 0, stream>>>(ei, flags, rowptr, cnt, colx);
  prep_kernel<<<dim3(1584), dim3(256), 0, stream>>>(
      Wl, Wr, Wlin, fWl, fWr, fWlin, flags, wpack, fwp);

  // ---- layer 0: A = raw x (dtype-switched) fused into A-load ----
  gemm_kernel<<<dim3((NN + 63) / 64), dim3(256), 0, stream>>>(
      x, wpack, blin, flags, 0, xl, xr, lpA, NN, cpart, lpA, ab, 2);
  agg_kernel<<<dim3(NN / 4), dim3(256), 0, stream>>>(xl, xr, rowptr, colx, att, bconv,
                                                     flags, 0, cpart);
  stats_kernel<<<dim3(500), dim3(256), 0, stream>>>(cpart, sums);
  nprep_kernel<<<dim3(1), dim3(256), 0, stream>>>(sums, gnw, gnb, gnms, flags, 0, ab);

  // ---- layer 1: A = elu(norm(cpart) + lpA) fused into A-load ----
  gemm_kernel<<<dim3((NN + 63) / 64), dim3(256), 0, stream>>>(
      x, wpack + (size_t)3 * 65536, blin, flags, 1, xl, xr, lpB, NN, cpart, lpA, ab, 1);
  agg_kernel<<<dim3(NN / 4), dim3(256), 0, stream>>>(xl, xr, rowptr, colx, att, bconv,
                                                     flags, 1, cpart);
  stats_kernel<<<dim3(500), dim3(256), 0, stream>>>(cpart, sums + 512);
  nprep_kernel<<<dim3(1), dim3(256), 0, stream>>>(sums, gnw, gnb, gnms, flags, 1, ab + 512);

  // ---- final: A = elu(norm(cpart) + lpB) fused ----
  fgemm_kernel<<<dim3((NN + 63) / 64), dim3(256), 0, stream>>>(
      cpart, lpB, ab + 512, fwp, fblin, flags, zl, zr, lp5, NN);
  finagg_kernel<<<dim3(NN / 4), dim3(256), 0, stream>>>(zl, zr, rowptr, colx, fatt, fbc,
                                                        flags, lp5, d_out);
}